// Round 3
// baseline (10093.587 us; speedup 1.0000x reference)
//
#include <hip/hip_runtime.h>
#include <hip/hip_bf16.h>
#include <math.h>

#define B_  256
#define T_  256
#define IN_ 4
#define HP_ 64
#define E_  512
#define H_  1024
#define D_  4

typedef __hip_bfloat16 bf16;

// ---------------------------------------------------------------------------
// Dual-dtype load helpers: flag!=0 -> input arrays are bf16, else fp32.
// bf16 -> f32 via exact bit shift.
// ---------------------------------------------------------------------------
__device__ __forceinline__ float load1(const void* p, size_t idx, bool isb) {
    if (isb) {
        unsigned int u = ((const unsigned short*)p)[idx];
        return __uint_as_float(u << 16);
    }
    return ((const float*)p)[idx];
}

__device__ __forceinline__ float4 load4(const void* p, size_t idx, bool isb) {
    // idx must be a multiple of 4 (8B-aligned bf16 path, 16B-aligned f32 path)
    if (isb) {
        ushort4 u = *(const ushort4*)((const unsigned short*)p + idx);
        float4 r;
        r.x = __uint_as_float(((unsigned int)u.x) << 16);
        r.y = __uint_as_float(((unsigned int)u.y) << 16);
        r.z = __uint_as_float(((unsigned int)u.z) << 16);
        r.w = __uint_as_float(((unsigned int)u.w) << 16);
        return r;
    }
    return *((const float4*)p + (idx >> 2));
}

// ---------------------------------------------------------------------------
// Dtype sniff: reinterpret first 64K ushorts of hist_feat as bf16. Real fp32
// data -> even-indexed ushorts are random mantissa bits -> ~20%+ insane
// magnitudes. Real bf16 N(0,1) data -> none. flag: 1 = bf16, 0 = fp32.
// ---------------------------------------------------------------------------
__global__ void sniff_kernel(const unsigned short* __restrict__ p,
                             int* __restrict__ flag) {
    __shared__ int cnt;
    if (threadIdx.x == 0) cnt = 0;
    __syncthreads();
    int local = 0;
    for (int i = threadIdx.x; i < 65536; i += blockDim.x) {
        unsigned int bits = ((unsigned int)p[i]) << 16;
        float v = __uint_as_float(bits);
        float a = fabsf(v);
        if (!(a <= 1e4f)) local++;                  // huge or NaN
        else if (v != 0.0f && a < 1e-6f) local++;   // absurdly tiny
    }
    atomicAdd(&cnt, local);
    __syncthreads();
    if (threadIdx.x == 0) *flag = (cnt > 1024) ? 0 : 1;
}

// ---------------------------------------------------------------------------
// Projector: Xc[m,:] = gelu(hist[gm,:] @ pW1 + pb1, exact) @ pW2 + pb2
// One block per chunk-local row m; gm = m0 + m is the global (b*T+t) row.
// ---------------------------------------------------------------------------
__global__ __launch_bounds__(256) void proj_kernel(
        const void* __restrict__ hist, const void* __restrict__ pW1,
        const void* __restrict__ pb1,  const void* __restrict__ pW2,
        const void* __restrict__ pb2,  float* __restrict__ Xc,
        size_t m0, const int* __restrict__ flag) {
    const bool isb = (*flag != 0);
    __shared__ float h1[HP_];
    __shared__ float hrow[IN_];
    size_t m = blockIdx.x;
    size_t gm = m0 + m;
    int tid = threadIdx.x;
    if (tid < IN_) hrow[tid] = load1(hist, gm * IN_ + tid, isb);
    __syncthreads();
    if (tid < HP_) {
        float acc = 0.f;
        #pragma unroll
        for (int i = 0; i < IN_; ++i)
            acc = fmaf(hrow[i], load1(pW1, (size_t)i * HP_ + tid, isb), acc);
        acc += load1(pb1, tid, isb);
        // exact GELU: 0.5*x*(1+erf(x/sqrt(2)))
        h1[tid] = 0.5f * acc * (1.0f + erff(acc * 0.70710678118654752440f));
    }
    __syncthreads();
    for (int e = tid; e < E_; e += 256) {
        float acc = 0.f;
        #pragma unroll 8
        for (int i = 0; i < HP_; ++i)
            acc = fmaf(h1[i], load1(pW2, (size_t)i * E_ + e, isb), acc);
        acc += load1(pb2, e, isb);
        Xc[m * E_ + e] = acc;
    }
}

// ---------------------------------------------------------------------------
// Tiled fp32 GEMM: C[R,N] = A[R,K] @ W[K,N] + bias.  128x128 tile, BK=16,
// 512 threads, 8x4 micro-tile (rows split in two 4-row halves 64 apart).
//   - per-thread issue per tile ~1072 cyc (512 FMA + 48 ds_read) and ~70
//     VGPRs -> launch_bounds(512,6) -> up to 3 blocks (24 waves) per CU,
//     6 waves/SIMD of latency hiding (vs 1.5 blocks for the 256-thr 8x8).
//   - A-fragment LDS reads are 2-address broadcasts; B-reads are 512B
//     all-bank sweeps with 2-lane broadcast -> LDS pipe <10% loaded.
//   - staging: exactly one float4 of A + one float4 of B per thread/tile.
// Double-buffered LDS, ONE __syncthreads per k-tile; next tile's global
// loads issue right after the barrier so HBM latency hides under the FMAs.
// Accumulation per output element is one fmaf per k in ascending k order
// + bias add afterwards: BIT-IDENTICAL numerics to all prior versions.
// ---------------------------------------------------------------------------
__global__ __launch_bounds__(512, 6) void gemm_bias_kernel(
        const float* __restrict__ A, const void* __restrict__ W, size_t wOff,
        const void* __restrict__ bias, size_t bOff,
        float* __restrict__ C, int N, int K, const int* __restrict__ flag) {
    const bool isb = (*flag != 0);
    __shared__ float As[2][16][128];   // k-major A tile (transposed on store)
    __shared__ float Bs[2][16][132];   // +4 pad keeps store banks balanced
    const int bn = blockIdx.x * 128;
    const int bm = blockIdx.y * 128;
    const int tid = threadIdx.x;

    // staging indices: one float4 of A, one float4 of B per thread per tile
    const int ar = tid >> 2;           // 0..127 : A tile row
    const int ak = (tid & 3) << 2;     // 0,4,8,12 : A k base (float4)
    const int wr = tid >> 5;           // 0..15  : W tile k-row
    const int wc = (tid & 31) << 2;    // 0..124 : W tile col base (float4)

    // compute indices (16 row-groups x 32 col-groups, 8x4 microtile)
    const int rg = tid >> 5;           // 0..15 : row group
    const int cg = tid & 31;           // 0..31 : col group

    float acc[8][4];
    #pragma unroll
    for (int i = 0; i < 8; ++i)
        #pragma unroll
        for (int j = 0; j < 4; ++j) acc[i][j] = 0.f;

    const float* Ap = A + (size_t)(bm + ar) * K + ak;
    const size_t wBase = wOff + (size_t)wr * N + bn + wc;

    // prologue: stage tile 0 into regs
    float4 a0 = *(const float4*)(Ap);
    float4 w0 = load4(W, wBase, isb);

    const int nt = K >> 4;
    for (int t = 0; t < nt; ++t) {
        const int cur = t & 1;
        // write staged regs to LDS buffer `cur`
        As[cur][ak + 0][ar] = a0.x; As[cur][ak + 1][ar] = a0.y;
        As[cur][ak + 2][ar] = a0.z; As[cur][ak + 3][ar] = a0.w;
        *(float4*)&Bs[cur][wr][wc] = w0;
        __syncthreads();
        // issue next tile's global loads (completion awaited at next store)
        if (t + 1 < nt) {
            const int k0 = (t + 1) << 4;
            a0 = *(const float4*)(Ap + k0);
            w0 = load4(W, wBase + (size_t)k0 * N, isb);
        }
        #pragma unroll
        for (int k = 0; k < 16; ++k) {
            float a[8], b[4];
            *(float4*)&a[0] = *(const float4*)&As[cur][k][rg * 4];
            *(float4*)&a[4] = *(const float4*)&As[cur][k][64 + rg * 4];
            *(float4*)&b[0] = *(const float4*)&Bs[cur][k][cg * 4];
            #pragma unroll
            for (int i = 0; i < 8; ++i)
                #pragma unroll
                for (int j = 0; j < 4; ++j)
                    acc[i][j] = fmaf(a[i], b[j], acc[i][j]);
        }
    }
    const int col = bn + cg * 4;
    float4 bv;
    bv.x = load1(bias, bOff + col + 0, isb);
    bv.y = load1(bias, bOff + col + 1, isb);
    bv.z = load1(bias, bOff + col + 2, isb);
    bv.w = load1(bias, bOff + col + 3, isb);
    #pragma unroll
    for (int ih = 0; ih < 2; ++ih) {
        #pragma unroll
        for (int i4 = 0; i4 < 4; ++i4) {
            const int i = (ih << 2) + i4;
            size_t row = (size_t)(bm + (ih << 6) + rg * 4 + i4);
            float4 o;
            o.x = acc[i][0] + bv.x;
            o.y = acc[i][1] + bv.y;
            o.z = acc[i][2] + bv.z;
            o.w = acc[i][3] + bv.w;
            *(float4*)(C + row * N + col) = o;
        }
    }
}

// ---------------------------------------------------------------------------
// Row-wise LayerNorm, in place. One block (256 thr) per row, two-pass.
// ---------------------------------------------------------------------------
__device__ __forceinline__ float block_sum(float v, float* smem, int tid) {
    #pragma unroll
    for (int off = 32; off > 0; off >>= 1) v += __shfl_down(v, off, 64);
    __syncthreads();
    if ((tid & 63) == 0) smem[tid >> 6] = v;
    __syncthreads();
    if (tid == 0) smem[4] = smem[0] + smem[1] + smem[2] + smem[3];
    __syncthreads();
    return smem[4];
}

__global__ __launch_bounds__(256) void ln_kernel(float* __restrict__ Y,
        const void* __restrict__ g, size_t gOff,
        const void* __restrict__ b, size_t bOff,
        int N, const int* __restrict__ flag) {
    const bool isb = (*flag != 0);
    __shared__ float smem[5];
    size_t row = blockIdx.x;
    float* y = Y + row * (size_t)N;
    int tid = threadIdx.x;
    int nPer = N >> 8;   // 4 for N=1024, 2 for N=512
    float vals[4];
    float s = 0.f;
    for (int i = 0; i < nPer; ++i) { float v = y[tid + (i << 8)]; vals[i] = v; s += v; }
    float mean = block_sum(s, smem, tid) / (float)N;
    float sq = 0.f;
    for (int i = 0; i < nPer; ++i) { float d0 = vals[i] - mean; sq += d0 * d0; }
    float var = block_sum(sq, smem, tid) / (float)N;
    float denom = sqrtf(var + 1e-5f);
    for (int i = 0; i < nPer; ++i) {
        int c = tid + (i << 8);
        y[c] = (vals[i] - mean) / denom * load1(g, gOff + c, isb) + load1(b, bOff + c, isb);
    }
}

// ---------------------------------------------------------------------------
// LIF scan over T, in place. Thread per (local b, feature), coalesced per t.
// v += (x - v)/2 ; s = (v-1 >= 0) ; hard reset v *= (1-s).
// ---------------------------------------------------------------------------
__global__ __launch_bounds__(256) void lif_kernel(float* __restrict__ Y, int N) {
    int f = blockIdx.x * 256 + threadIdx.x;
    int b = blockIdx.y;
    size_t base = (size_t)b * T_ * N + f;
    float v = 0.f;
    for (int t = 0; t < T_; ++t) {
        size_t idx = base + (size_t)t * N;
        float x = Y[idx];
        v = v + (x - v) * 0.5f;
        float s = (v - 1.0f >= 0.0f) ? 1.0f : 0.0f;
        v = v * (1.0f - s);
        Y[idx] = s;
    }
}

// Second LIF of a layer fused with residual add into Xc.
__global__ __launch_bounds__(256) void lif_add_kernel(const float* __restrict__ Z,
                                                      float* __restrict__ Xc) {
    int e = blockIdx.x * 256 + threadIdx.x;
    int b = blockIdx.y;
    size_t base = (size_t)b * T_ * E_ + e;
    float v = 0.f;
    for (int t = 0; t < T_; ++t) {
        size_t idx = base + (size_t)t * E_;
        float x = Z[idx];
        v = v + (x - v) * 0.5f;
        float s = (v - 1.0f >= 0.0f) ? 1.0f : 0.0f;
        v = v * (1.0f - s);
        Xc[idx] += s;
    }
}

// Gather chunk rows t=T-1 -> out[b0+bl, :], encode bf16/fp32 per flag.
__global__ void out_kernel(const float* __restrict__ Xc, void* __restrict__ out,
                           int b0, const int* __restrict__ flag) {
    int i = blockIdx.x * 256 + threadIdx.x;   // 0 .. CB*E_-1
    int bl = i / E_, e = i - bl * E_;
    float v = Xc[((size_t)bl * T_ + (T_ - 1)) * E_ + e];
    size_t oi = (size_t)(b0 + bl) * E_ + e;
    if (*flag) ((bf16*)out)[oi] = __float2bfloat16(v);
    else       ((float*)out)[oi] = v;
}

// ---------------------------------------------------------------------------
extern "C" void kernel_launch(void* const* d_in, const int* in_sizes, int n_in,
                              void* d_out, int out_size, void* d_ws, size_t ws_size,
                              hipStream_t stream) {
    char* ws = (char*)d_ws;
    int* flag = (int*)ws;

    // Chunk over batches so workspace fits: per chunk of CB batches we need
    // CB*T*(E + H + E)*4 bytes = CB * 2 MiB.
    size_t avail = (ws_size > 256) ? ws_size - 256 : 0;
    int CB = 256;
    while (CB > 1 && (size_t)CB * T_ * (size_t)(E_ + H_ + E_) * 4 > avail) CB >>= 1;
    const int R = CB * T_;

    float* Xc  = (float*)(ws + 256);
    float* HBc = Xc + (size_t)R * E_;
    float* Y2c = HBc + (size_t)R * H_;

    sniff_kernel<<<1, 256, 0, stream>>>((const unsigned short*)d_in[0], flag);

    for (int b0 = 0; b0 < B_; b0 += CB) {
        proj_kernel<<<R, 256, 0, stream>>>(d_in[0], d_in[1], d_in[2], d_in[3],
                                           d_in[4], Xc, (size_t)b0 * T_, flag);
        for (int d = 0; d < D_; ++d) {
            size_t w1o = (size_t)d * E_ * H_, b1o = (size_t)d * H_;
            size_t w2o = (size_t)d * H_ * E_, b2o = (size_t)d * E_;

            gemm_bias_kernel<<<dim3(H_ / 128, R / 128), 512, 0, stream>>>(
                Xc, d_in[5], w1o, d_in[6], b1o, HBc, H_, E_, flag);
            ln_kernel<<<R, 256, 0, stream>>>(HBc, d_in[7], b1o, d_in[8], b1o, H_, flag);
            lif_kernel<<<dim3(H_ / 256, CB), 256, 0, stream>>>(HBc, H_);

            gemm_bias_kernel<<<dim3(E_ / 128, R / 128), 512, 0, stream>>>(
                HBc, d_in[9], w2o, d_in[10], b2o, Y2c, E_, H_, flag);
            ln_kernel<<<R, 256, 0, stream>>>(Y2c, d_in[11], b2o, d_in[12], b2o, E_, flag);
            lif_add_kernel<<<dim3(E_ / 256, CB), 256, 0, stream>>>(Y2c, Xc);
        }
        out_kernel<<<(CB * E_) / 256, 256, 0, stream>>>(Xc, d_out, b0, flag);
    }
}

// Round 4
// 6332.030 us; speedup vs baseline: 1.5941x; 1.5941x over previous
//
#include <hip/hip_runtime.h>
#include <hip/hip_bf16.h>
#include <math.h>

#define B_  256
#define T_  256
#define IN_ 4
#define HP_ 64
#define E_  512
#define H_  1024
#define D_  4

typedef __hip_bfloat16 bf16;
typedef _Float16 f16;
typedef _Float16 f16x8 __attribute__((ext_vector_type(8)));
typedef float f32x4 __attribute__((ext_vector_type(4)));

// ---------------------------------------------------------------------------
// Dual-dtype load helpers: flag!=0 -> input arrays are bf16, else fp32.
// ---------------------------------------------------------------------------
__device__ __forceinline__ float load1(const void* p, size_t idx, bool isb) {
    if (isb) {
        unsigned int u = ((const unsigned short*)p)[idx];
        return __uint_as_float(u << 16);
    }
    return ((const float*)p)[idx];
}

__device__ __forceinline__ float4 load4(const void* p, size_t idx, bool isb) {
    if (isb) {
        ushort4 u = *(const ushort4*)((const unsigned short*)p + idx);
        float4 r;
        r.x = __uint_as_float(((unsigned int)u.x) << 16);
        r.y = __uint_as_float(((unsigned int)u.y) << 16);
        r.z = __uint_as_float(((unsigned int)u.z) << 16);
        r.w = __uint_as_float(((unsigned int)u.w) << 16);
        return r;
    }
    return *((const float4*)p + (idx >> 2));
}

// ---------------------------------------------------------------------------
// Exact 3-plane f16 split:  x ~= h + lb*2^-11   (lo stored pre-scaled by 2^11
// so it never hits f16 subnormal flush; hs = h*2^-11 is the matching partner)
// x*w = h*wh + (h*2^-11)*(wl*2^11) + (l*2^11)*(wh*2^-11)   [all exact terms]
// ---------------------------------------------------------------------------
__device__ __forceinline__ void split3(float x, f16& h, f16& hs, f16& lb) {
    h = (f16)x;
    float hf = (float)h;
    hs = (f16)(hf * 4.8828125e-4f);        // *2^-11, exact exponent shift
    lb = (f16)((x - hf) * 2048.0f);        // residual, pre-scaled *2^11
}

// ---------------------------------------------------------------------------
// Dtype sniff (unchanged).
// ---------------------------------------------------------------------------
__global__ void sniff_kernel(const unsigned short* __restrict__ p,
                             int* __restrict__ flag) {
    __shared__ int cnt;
    if (threadIdx.x == 0) cnt = 0;
    __syncthreads();
    int local = 0;
    for (int i = threadIdx.x; i < 65536; i += blockDim.x) {
        unsigned int bits = ((unsigned int)p[i]) << 16;
        float v = __uint_as_float(bits);
        float a = fabsf(v);
        if (!(a <= 1e4f)) local++;
        else if (v != 0.0f && a < 1e-6f) local++;
    }
    atomicAdd(&cnt, local);
    __syncthreads();
    if (threadIdx.x == 0) *flag = (cnt > 1024) ? 0 : 1;
}

// ---------------------------------------------------------------------------
// Weight transpose+split: W[K][N] (fp32/bf16) -> Wt ushort[N][3K]:
// per n-row: [hi(k=0..K-1) | hi*2^-11 | lo*2^11]  (f16 bit patterns).
// Grid (N/32, K/32), 256 threads, LDS 32x32 transpose.
// ---------------------------------------------------------------------------
__global__ __launch_bounds__(256) void wsplit_kernel(
        const void* __restrict__ W, size_t wOff, unsigned short* __restrict__ Wt,
        int K, int N, const int* __restrict__ flag) {
    const bool isb = (*flag != 0);
    __shared__ float tile[32][33];
    const int n0 = blockIdx.x * 32, k0 = blockIdx.y * 32;
    const int t = threadIdx.x;
    {
        int lk = t >> 3, ln0 = (t & 7) << 2;
        float4 v = load4(W, wOff + (size_t)(k0 + lk) * N + n0 + ln0, isb);
        tile[lk][ln0 + 0] = v.x; tile[lk][ln0 + 1] = v.y;
        tile[lk][ln0 + 2] = v.z; tile[lk][ln0 + 3] = v.w;
    }
    __syncthreads();
    int n = t >> 3, kq0 = (t & 7) << 2;
    size_t base = (size_t)(n0 + n) * (3 * (size_t)K) + k0 + kq0;
    #pragma unroll
    for (int j = 0; j < 4; ++j) {
        float x = tile[kq0 + j][n];
        f16 h, hs, lb;
        split3(x, h, hs, lb);
        Wt[base + j]         = *(unsigned short*)&h;
        Wt[base + j + K]     = *(unsigned short*)&hs;
        Wt[base + j + 2 * K] = *(unsigned short*)&lb;
    }
}

// ---------------------------------------------------------------------------
// MFMA GEMM: C[R,N] = A[R,K] @ W[K,N] + bias, fp32-accurate via 3-plane f16
// split (error ~2^-22 rel, below fp32-ordering noise).
//   tile 128(M) x 64(N), BK=32, 256 thr = 4 waves as 2x2, wave-tile 64x32,
//   mfma_f32_16x16x32_f16, acc 4x2 f32x4 frags.
// LDS: row = 256B = 16 slots of 16B; logical slot (plane p, kgroup g) stored
// at slot ((p<<2)|g) ^ (row&7)  -> frag reads (fixed p,g, rows vary) hit all
// 32 banks 2-deep = conflict-free. Same map used on write & read.
// k map: lane-group g holds k = g*8 + j for BOTH operands -> any HW-internal
// k permutation cancels. C/D map (m89-verified): col=lane&15,
// row=(lane>>4)*4+reg.
// ---------------------------------------------------------------------------
__global__ __launch_bounds__(256, 3) void gemm_mfma_kernel(
        const float* __restrict__ A, const unsigned short* __restrict__ Wt,
        const void* __restrict__ bias, size_t bOff,
        float* __restrict__ C, int N, int K, const int* __restrict__ flag) {
    const bool isb = (*flag != 0);
    __shared__ unsigned short As[128 * 128];   // 128 rows x 256B = 32 KB
    __shared__ unsigned short Bs[64 * 128];    // 64 rows x 256B = 16 KB
    const int bn = blockIdx.x * 64;
    const int bm = blockIdx.y * 128;
    const int tid  = threadIdx.x;
    const int lane = tid & 63;
    const int wave = tid >> 6;
    const int wm = wave >> 1;          // 0..1 : wave row block (64 rows)
    const int wn = wave & 1;           // 0..1 : wave col block (32 cols)
    const int g  = lane >> 4;          // k-group 0..3 (k = g*8+j)
    const int lr = lane & 15;

    // A staging: thread -> (row, k-half)
    const int sar = tid >> 1;          // 0..127
    const int sah = tid & 1;           // 0..1 : k 0..15 / 16..31
    // B staging: thread -> (n-row, k-group)
    const int sbn = tid >> 2;          // 0..63
    const int sbq = tid & 3;           // 0..3

    f32x4 acc[4][2];
    #pragma unroll
    for (int i = 0; i < 4; ++i)
        #pragma unroll
        for (int j = 0; j < 2; ++j) acc[i][j] = (f32x4){0.f, 0.f, 0.f, 0.f};

    const float* Ap = A + (size_t)(bm + sar) * K + sah * 16;
    const unsigned short* Wp = Wt + (size_t)(bn + sbn) * (3 * (size_t)K) + sbq * 8;

    for (int k0 = 0; k0 < K; k0 += 32) {
        // ---- stage A: load 16 f32 along k, split to 3 planes, 6x b128 ----
        float x[16];
        #pragma unroll
        for (int c = 0; c < 4; ++c) {
            float4 v = *(const float4*)(Ap + k0 + c * 4);
            x[c * 4 + 0] = v.x; x[c * 4 + 1] = v.y;
            x[c * 4 + 2] = v.z; x[c * 4 + 3] = v.w;
        }
        #pragma unroll
        for (int c = 0; c < 2; ++c) {
            f16x8 h8, s8, l8;
            #pragma unroll
            for (int j = 0; j < 8; ++j) {
                f16 h, hs, lb;
                split3(x[c * 8 + j], h, hs, lb);
                h8[j] = h; s8[j] = hs; l8[j] = lb;
            }
            const int gg = sah * 2 + c;
            const int rb = sar * 128;
            const int sw = sar & 7;
            *(f16x8*)&As[rb + (((0 << 2) | gg) ^ sw) * 8] = h8;
            *(f16x8*)&As[rb + (((1 << 2) | gg) ^ sw) * 8] = s8;
            *(f16x8*)&As[rb + (((2 << 2) | gg) ^ sw) * 8] = l8;
        }
        // ---- stage B: copy 3 planes' 16B chunks from Wt ----
        {
            const int rb = sbn * 128;
            const int sw = sbn & 7;
            #pragma unroll
            for (int p = 0; p < 3; ++p) {
                f16x8 v = *(const f16x8*)(Wp + (size_t)p * K + k0);
                *(f16x8*)&Bs[rb + (((p << 2) | sbq) ^ sw) * 8] = v;
            }
        }
        __syncthreads();
        // ---- compute: 3 exact product planes ----
        // pairs: (A_hi,B_hi), (A_his,B_lob), (A_lob,B_his)
        const int PA[3] = {0, 1, 2};
        const int PB[3] = {0, 2, 1};
        #pragma unroll
        for (int p = 0; p < 3; ++p) {
            const int pa = PA[p], pb = PB[p];
            f16x8 af[4], bf[2];
            #pragma unroll
            for (int mi = 0; mi < 4; ++mi) {
                const int ar = wm * 64 + mi * 16 + lr;
                af[mi] = *(const f16x8*)&As[ar * 128 + (((pa << 2) | g) ^ (ar & 7)) * 8];
            }
            #pragma unroll
            for (int ni = 0; ni < 2; ++ni) {
                const int br = wn * 32 + ni * 16 + lr;
                bf[ni] = *(const f16x8*)&Bs[br * 128 + (((pb << 2) | g) ^ (br & 7)) * 8];
            }
            #pragma unroll
            for (int mi = 0; mi < 4; ++mi)
                #pragma unroll
                for (int ni = 0; ni < 2; ++ni)
                    acc[mi][ni] = __builtin_amdgcn_mfma_f32_16x16x32_f16(
                        af[mi], bf[ni], acc[mi][ni], 0, 0, 0);
        }
        __syncthreads();
    }
    // ---- epilogue: C/D map col=lane&15, row=(lane>>4)*4+reg ----
    #pragma unroll
    for (int ni = 0; ni < 2; ++ni) {
        const int col = bn + wn * 32 + ni * 16 + lr;
        const float bv = load1(bias, bOff + col, isb);
        #pragma unroll
        for (int mi = 0; mi < 4; ++mi) {
            #pragma unroll
            for (int r = 0; r < 4; ++r) {
                const size_t row = (size_t)(bm + wm * 64 + mi * 16 + g * 4 + r);
                C[row * N + col] = acc[mi][ni][r] + bv;
            }
        }
    }
}

// ---------------------------------------------------------------------------
// Projector (unchanged).
// ---------------------------------------------------------------------------
__global__ __launch_bounds__(256) void proj_kernel(
        const void* __restrict__ hist, const void* __restrict__ pW1,
        const void* __restrict__ pb1,  const void* __restrict__ pW2,
        const void* __restrict__ pb2,  float* __restrict__ Xc,
        size_t m0, const int* __restrict__ flag) {
    const bool isb = (*flag != 0);
    __shared__ float h1[HP_];
    __shared__ float hrow[IN_];
    size_t m = blockIdx.x;
    size_t gm = m0 + m;
    int tid = threadIdx.x;
    if (tid < IN_) hrow[tid] = load1(hist, gm * IN_ + tid, isb);
    __syncthreads();
    if (tid < HP_) {
        float acc = 0.f;
        #pragma unroll
        for (int i = 0; i < IN_; ++i)
            acc = fmaf(hrow[i], load1(pW1, (size_t)i * HP_ + tid, isb), acc);
        acc += load1(pb1, tid, isb);
        h1[tid] = 0.5f * acc * (1.0f + erff(acc * 0.70710678118654752440f));
    }
    __syncthreads();
    for (int e = tid; e < E_; e += 256) {
        float acc = 0.f;
        #pragma unroll 8
        for (int i = 0; i < HP_; ++i)
            acc = fmaf(h1[i], load1(pW2, (size_t)i * E_ + e, isb), acc);
        acc += load1(pb2, e, isb);
        Xc[m * E_ + e] = acc;
    }
}

// ---------------------------------------------------------------------------
// LayerNorm (unchanged).
// ---------------------------------------------------------------------------
__device__ __forceinline__ float block_sum(float v, float* smem, int tid) {
    #pragma unroll
    for (int off = 32; off > 0; off >>= 1) v += __shfl_down(v, off, 64);
    __syncthreads();
    if ((tid & 63) == 0) smem[tid >> 6] = v;
    __syncthreads();
    if (tid == 0) smem[4] = smem[0] + smem[1] + smem[2] + smem[3];
    __syncthreads();
    return smem[4];
}

__global__ __launch_bounds__(256) void ln_kernel(float* __restrict__ Y,
        const void* __restrict__ g, size_t gOff,
        const void* __restrict__ b, size_t bOff,
        int N, const int* __restrict__ flag) {
    const bool isb = (*flag != 0);
    __shared__ float smem[5];
    size_t row = blockIdx.x;
    float* y = Y + row * (size_t)N;
    int tid = threadIdx.x;
    int nPer = N >> 8;
    float vals[4];
    float s = 0.f;
    for (int i = 0; i < nPer; ++i) { float v = y[tid + (i << 8)]; vals[i] = v; s += v; }
    float mean = block_sum(s, smem, tid) / (float)N;
    float sq = 0.f;
    for (int i = 0; i < nPer; ++i) { float d0 = vals[i] - mean; sq += d0 * d0; }
    float var = block_sum(sq, smem, tid) / (float)N;
    float denom = sqrtf(var + 1e-5f);
    for (int i = 0; i < nPer; ++i) {
        int c = tid + (i << 8);
        y[c] = (vals[i] - mean) / denom * load1(g, gOff + c, isb) + load1(b, bOff + c, isb);
    }
}

// ---------------------------------------------------------------------------
// LIF kernels (unchanged).
// ---------------------------------------------------------------------------
__global__ __launch_bounds__(256) void lif_kernel(float* __restrict__ Y, int N) {
    int f = blockIdx.x * 256 + threadIdx.x;
    int b = blockIdx.y;
    size_t base = (size_t)b * T_ * N + f;
    float v = 0.f;
    for (int t = 0; t < T_; ++t) {
        size_t idx = base + (size_t)t * N;
        float x = Y[idx];
        v = v + (x - v) * 0.5f;
        float s = (v - 1.0f >= 0.0f) ? 1.0f : 0.0f;
        v = v * (1.0f - s);
        Y[idx] = s;
    }
}

__global__ __launch_bounds__(256) void lif_add_kernel(const float* __restrict__ Z,
                                                      float* __restrict__ Xc) {
    int e = blockIdx.x * 256 + threadIdx.x;
    int b = blockIdx.y;
    size_t base = (size_t)b * T_ * E_ + e;
    float v = 0.f;
    for (int t = 0; t < T_; ++t) {
        size_t idx = base + (size_t)t * E_;
        float x = Z[idx];
        v = v + (x - v) * 0.5f;
        float s = (v - 1.0f >= 0.0f) ? 1.0f : 0.0f;
        v = v * (1.0f - s);
        Xc[idx] += s;
    }
}

__global__ void out_kernel(const float* __restrict__ Xc, void* __restrict__ out,
                           int b0, const int* __restrict__ flag) {
    int i = blockIdx.x * 256 + threadIdx.x;
    int bl = i / E_, e = i - bl * E_;
    float v = Xc[((size_t)bl * T_ + (T_ - 1)) * E_ + e];
    size_t oi = (size_t)(b0 + bl) * E_ + e;
    if (*flag) ((bf16*)out)[oi] = __float2bfloat16(v);
    else       ((float*)out)[oi] = v;
}

// ---------------------------------------------------------------------------
extern "C" void kernel_launch(void* const* d_in, const int* in_sizes, int n_in,
                              void* d_out, int out_size, void* d_ws, size_t ws_size,
                              hipStream_t stream) {
    char* ws = (char*)d_ws;
    int* flag = (int*)ws;

    // Wt area: per matrix 3*K*N = 3*524288 ushorts; 8 matrices (4 layers x 2).
    const size_t wtCount = 3 * (size_t)E_ * H_;          // ushorts per matrix
    const size_t wtBytes = 2 * D_ * wtCount * sizeof(unsigned short); // ~25.2 MB
    unsigned short* Wt1 = (unsigned short*)(ws + 256);
    unsigned short* Wt2 = Wt1 + (size_t)D_ * wtCount;

    size_t used = 256 + wtBytes;
    size_t avail = (ws_size > used) ? ws_size - used : 0;
    int CB = 256;
    while (CB > 1 && (size_t)CB * T_ * (size_t)(E_ + H_ + E_) * 4 > avail) CB >>= 1;
    const int R = CB * T_;

    float* Xc  = (float*)(ws + used);
    float* HBc = Xc + (size_t)R * E_;
    float* Y2c = HBc + (size_t)R * H_;

    sniff_kernel<<<1, 256, 0, stream>>>((const unsigned short*)d_in[0], flag);

    // Precompute transposed+split weights once.
    for (int d = 0; d < D_; ++d) {
        wsplit_kernel<<<dim3(H_ / 32, E_ / 32), 256, 0, stream>>>(
            d_in[5], (size_t)d * E_ * H_, Wt1 + (size_t)d * wtCount, E_, H_, flag);
        wsplit_kernel<<<dim3(E_ / 32, H_ / 32), 256, 0, stream>>>(
            d_in[9], (size_t)d * H_ * E_, Wt2 + (size_t)d * wtCount, H_, E_, flag);
    }

    for (int b0 = 0; b0 < B_; b0 += CB) {
        proj_kernel<<<R, 256, 0, stream>>>(d_in[0], d_in[1], d_in[2], d_in[3],
                                           d_in[4], Xc, (size_t)b0 * T_, flag);
        for (int d = 0; d < D_; ++d) {
            size_t b1o = (size_t)d * H_;
            size_t b2o = (size_t)d * E_;

            gemm_mfma_kernel<<<dim3(H_ / 64, R / 128), 256, 0, stream>>>(
                Xc, Wt1 + (size_t)d * wtCount, d_in[6], b1o, HBc, H_, E_, flag);
            ln_kernel<<<R, 256, 0, stream>>>(HBc, d_in[7], b1o, d_in[8], b1o, H_, flag);
            lif_kernel<<<dim3(H_ / 256, CB), 256, 0, stream>>>(HBc, H_);

            gemm_mfma_kernel<<<dim3(E_ / 64, R / 128), 256, 0, stream>>>(
                HBc, Wt2 + (size_t)d * wtCount, d_in[10], b2o, Y2c, E_, H_, flag);
            ln_kernel<<<R, 256, 0, stream>>>(Y2c, d_in[11], b2o, d_in[12], b2o, E_, flag);
            lif_add_kernel<<<dim3(E_ / 256, CB), 256, 0, stream>>>(Y2c, Xc);
        }
        out_kernel<<<(CB * E_) / 256, 256, 0, stream>>>(Xc, d_out, b0, flag);
    }
}

// Round 6
// 5184.385 us; speedup vs baseline: 1.9469x; 1.2214x over previous
//
#include <hip/hip_runtime.h>
#include <hip/hip_bf16.h>
#include <math.h>

#define B_  256
#define T_  256
#define IN_ 4
#define HP_ 64
#define E_  512
#define H_  1024
#define D_  4

typedef __hip_bfloat16 bf16;
typedef _Float16 f16;
typedef _Float16 f16x8 __attribute__((ext_vector_type(8)));
typedef float f32x4 __attribute__((ext_vector_type(4)));

// ---------------------------------------------------------------------------
// Dual-dtype load helpers: flag!=0 -> input arrays are bf16, else fp32.
// ---------------------------------------------------------------------------
__device__ __forceinline__ float load1(const void* p, size_t idx, bool isb) {
    if (isb) {
        unsigned int u = ((const unsigned short*)p)[idx];
        return __uint_as_float(u << 16);
    }
    return ((const float*)p)[idx];
}

__device__ __forceinline__ float4 load4(const void* p, size_t idx, bool isb) {
    if (isb) {
        ushort4 u = *(const ushort4*)((const unsigned short*)p + idx);
        float4 r;
        r.x = __uint_as_float(((unsigned int)u.x) << 16);
        r.y = __uint_as_float(((unsigned int)u.y) << 16);
        r.z = __uint_as_float(((unsigned int)u.z) << 16);
        r.w = __uint_as_float(((unsigned int)u.w) << 16);
        return r;
    }
    return *((const float4*)p + (idx >> 2));
}

// ---------------------------------------------------------------------------
// Exact 3-plane f16 split:  x ~= h + lb*2^-11   (lo stored pre-scaled by 2^11
// so it never hits f16 subnormal flush; hs = h*2^-11 is the matching partner)
// x*w = h*wh + (h*2^-11)*(wl*2^11) + (l*2^11)*(wh*2^-11)   [all exact terms]
// ---------------------------------------------------------------------------
__device__ __forceinline__ void split3(float x, f16& h, f16& hs, f16& lb) {
    h = (f16)x;
    float hf = (float)h;
    hs = (f16)(hf * 4.8828125e-4f);        // *2^-11, exact exponent shift
    lb = (f16)((x - hf) * 2048.0f);        // residual, pre-scaled *2^11
}

// ---------------------------------------------------------------------------
// Dtype sniff (unchanged).
// ---------------------------------------------------------------------------
__global__ void sniff_kernel(const unsigned short* __restrict__ p,
                             int* __restrict__ flag) {
    __shared__ int cnt;
    if (threadIdx.x == 0) cnt = 0;
    __syncthreads();
    int local = 0;
    for (int i = threadIdx.x; i < 65536; i += blockDim.x) {
        unsigned int bits = ((unsigned int)p[i]) << 16;
        float v = __uint_as_float(bits);
        float a = fabsf(v);
        if (!(a <= 1e4f)) local++;
        else if (v != 0.0f && a < 1e-6f) local++;
    }
    atomicAdd(&cnt, local);
    __syncthreads();
    if (threadIdx.x == 0) *flag = (cnt > 1024) ? 0 : 1;
}

// ---------------------------------------------------------------------------
// Weight transpose+split: W[K][N] (fp32/bf16) -> Wt ushort[N][3K]:
// per n-row: [hi(k=0..K-1) | hi*2^-11 | lo*2^11]  (f16 bit patterns).
// ---------------------------------------------------------------------------
__global__ __launch_bounds__(256) void wsplit_kernel(
        const void* __restrict__ W, size_t wOff, unsigned short* __restrict__ Wt,
        int K, int N, const int* __restrict__ flag) {
    const bool isb = (*flag != 0);
    __shared__ float tile[32][33];
    const int n0 = blockIdx.x * 32, k0 = blockIdx.y * 32;
    const int t = threadIdx.x;
    {
        int lk = t >> 3, ln0 = (t & 7) << 2;
        float4 v = load4(W, wOff + (size_t)(k0 + lk) * N + n0 + ln0, isb);
        tile[lk][ln0 + 0] = v.x; tile[lk][ln0 + 1] = v.y;
        tile[lk][ln0 + 2] = v.z; tile[lk][ln0 + 3] = v.w;
    }
    __syncthreads();
    int n = t >> 3, kq0 = (t & 7) << 2;
    size_t base = (size_t)(n0 + n) * (3 * (size_t)K) + k0 + kq0;
    #pragma unroll
    for (int j = 0; j < 4; ++j) {
        float x = tile[kq0 + j][n];
        f16 h, hs, lb;
        split3(x, h, hs, lb);
        Wt[base + j]         = *(unsigned short*)&h;
        Wt[base + j + K]     = *(unsigned short*)&hs;
        Wt[base + j + 2 * K] = *(unsigned short*)&lb;
    }
}

// ---------------------------------------------------------------------------
// MFMA GEMM: C[R,N] = A[R,K] @ W[K,N] + bias via 3-plane (or exact 2-plane
// when A is {0,1} spikes) f16 split.
//   tile 128(M) x 128(N), BK=32, 256 thr = 4 waves 2x2, wave-tile 64x64,
//   mfma_f32_16x16x32_f16, acc 4x4 f32x4.
// LDS row = 256B = 16 slots of 16B; slot (plane p, kgroup g) stored at
// ((p<<2)|g) ^ (row&7) -> frag reads & staged writes hit all 32 banks
// uniformly (8 dword-accesses per bank per wave64 b128 = conflict-free).
// Per block-ktile: LDS 144KB (1125cy) vs MFMA 6.3MF (1932cy) -> MFMA-bound.
// k map identical for A and B fragments -> internal k permutation cancels.
// C/D map (m89-verified, R4-validated): col=lane&15, row=(lane>>4)*4+reg.
// Numerics: per output element, planes accumulate in the same order per
// ascending k as R4 -> bit-identical output (2-plane drops an exact +0).
// ---------------------------------------------------------------------------
template<int NPL>
__device__ __forceinline__ void gemm_mfma_body(
        const float* __restrict__ A, const unsigned short* __restrict__ Wt,
        const void* __restrict__ bias, size_t bOff,
        float* __restrict__ C, int N, int K, const int* __restrict__ flag) {
    const bool isb = (*flag != 0);
    __shared__ unsigned short As[128 * 128];   // 32 KB
    __shared__ unsigned short Bs[128 * 128];   // 32 KB
    const int bn = blockIdx.x * 128;
    const int bm = blockIdx.y * 128;
    const int tid  = threadIdx.x;
    const int lane = tid & 63;
    const int wave = tid >> 6;
    const int wm = wave >> 1;          // 0..1 : wave row block (64 rows)
    const int wn = wave & 1;           // 0..1 : wave col block (64 cols)
    const int g  = lane >> 4;          // k-group 0..3 (k = g*8+j)
    const int lr = lane & 15;

    // A staging: thread -> (row 0..127, k-half 0..1)
    const int sar = tid >> 1;
    const int sah = tid & 1;
    // B staging: thread -> (n-row 0..127, k-group-pair 0..1)
    const int sbn = tid >> 1;
    const int sq  = tid & 1;

    // B planes actually staged/used: NPL=3 -> {0,1,2}; NPL=2 -> {0,2}
    const int NB = (NPL == 3) ? 3 : 2;
    const int BPL[3] = {0, (NPL == 3) ? 1 : 2, 2};

    f32x4 acc[4][4];
    #pragma unroll
    for (int i = 0; i < 4; ++i)
        #pragma unroll
        for (int j = 0; j < 4; ++j) acc[i][j] = (f32x4){0.f, 0.f, 0.f, 0.f};

    const float* Ap = A + (size_t)(bm + sar) * K + sah * 16;
    const unsigned short* Wp = Wt + (size_t)(bn + sbn) * (3 * (size_t)K) + sq * 16;

    // prologue: load tile 0 into regs
    float x[16];
    f16x8 wv[6];
    #pragma unroll
    for (int c = 0; c < 4; ++c) {
        float4 v = *(const float4*)(Ap + c * 4);
        x[c * 4 + 0] = v.x; x[c * 4 + 1] = v.y;
        x[c * 4 + 2] = v.z; x[c * 4 + 3] = v.w;
    }
    #pragma unroll
    for (int pi = 0; pi < NB; ++pi)
        #pragma unroll
        for (int c = 0; c < 2; ++c)
            wv[pi * 2 + c] = *(const f16x8*)(Wp + (size_t)BPL[pi] * K + c * 8);

    const int nt = K >> 5;
    for (int t = 0; t < nt; ++t) {
        // ---- store staged regs to LDS ----
        const int arb = sar * 128, asw = sar & 7;
        #pragma unroll
        for (int c = 0; c < 2; ++c) {
            f16x8 h8, s8, l8;
            #pragma unroll
            for (int j = 0; j < 8; ++j) {
                f16 h, hs, lb;
                split3(x[c * 8 + j], h, hs, lb);
                h8[j] = h; s8[j] = hs; l8[j] = lb;
            }
            const int gg = sah * 2 + c;
            *(f16x8*)&As[arb + (((0 << 2) | gg) ^ asw) * 8] = h8;
            *(f16x8*)&As[arb + (((1 << 2) | gg) ^ asw) * 8] = s8;
            if (NPL == 3)
                *(f16x8*)&As[arb + (((2 << 2) | gg) ^ asw) * 8] = l8;
        }
        const int brb = sbn * 128, bsw = sbn & 7;
        #pragma unroll
        for (int pi = 0; pi < NB; ++pi)
            #pragma unroll
            for (int c = 0; c < 2; ++c)
                *(f16x8*)&Bs[brb + (((BPL[pi] << 2) | (sq * 2 + c)) ^ bsw) * 8]
                    = wv[pi * 2 + c];
        __syncthreads();
        // ---- prefetch next tile into regs (latency hides under MFMAs) ----
        if (t + 1 < nt) {
            const int k0 = (t + 1) << 5;
            #pragma unroll
            for (int c = 0; c < 4; ++c) {
                float4 v = *(const float4*)(Ap + k0 + c * 4);
                x[c * 4 + 0] = v.x; x[c * 4 + 1] = v.y;
                x[c * 4 + 2] = v.z; x[c * 4 + 3] = v.w;
            }
            #pragma unroll
            for (int pi = 0; pi < NB; ++pi)
                #pragma unroll
                for (int c = 0; c < 2; ++c)
                    wv[pi * 2 + c] =
                        *(const f16x8*)(Wp + (size_t)BPL[pi] * K + k0 + c * 8);
        }
        // ---- compute: exact product planes, same order as R4 ----
        #pragma unroll
        for (int p = 0; p < NPL; ++p) {
            const int pa = p;
            const int pb = (p == 0) ? 0 : ((p == 1) ? 2 : 1);
            f16x8 af[4], bf[4];
            #pragma unroll
            for (int mi = 0; mi < 4; ++mi) {
                const int ar = wm * 64 + mi * 16 + lr;
                af[mi] = *(const f16x8*)&As[ar * 128 + (((pa << 2) | g) ^ (ar & 7)) * 8];
            }
            #pragma unroll
            for (int ni = 0; ni < 4; ++ni) {
                const int br = wn * 64 + ni * 16 + lr;
                bf[ni] = *(const f16x8*)&Bs[br * 128 + (((pb << 2) | g) ^ (br & 7)) * 8];
            }
            #pragma unroll
            for (int mi = 0; mi < 4; ++mi)
                #pragma unroll
                for (int ni = 0; ni < 4; ++ni)
                    acc[mi][ni] = __builtin_amdgcn_mfma_f32_16x16x32_f16(
                        af[mi], bf[ni], acc[mi][ni], 0, 0, 0);
        }
        __syncthreads();
    }
    // ---- epilogue: C/D map col=lane&15, row=(lane>>4)*4+reg ----
    #pragma unroll
    for (int ni = 0; ni < 4; ++ni) {
        const int col = bn + wn * 64 + ni * 16 + lr;
        const float bv = load1(bias, bOff + col, isb);
        #pragma unroll
        for (int mi = 0; mi < 4; ++mi) {
            #pragma unroll
            for (int r = 0; r < 4; ++r) {
                const size_t row = (size_t)(bm + wm * 64 + mi * 16 + g * 4 + r);
                C[row * N + col] = acc[mi][ni][r] + bv;
            }
        }
    }
}

__global__ __launch_bounds__(256, 2) void gemm_mfma3_kernel(
        const float* __restrict__ A, const unsigned short* __restrict__ Wt,
        const void* __restrict__ bias, size_t bOff,
        float* __restrict__ C, int N, int K, const int* __restrict__ flag) {
    gemm_mfma_body<3>(A, Wt, bias, bOff, C, N, K, flag);
}

// A is exact {0,1} spikes -> lo-plane is exactly zero -> 2 planes suffice.
__global__ __launch_bounds__(256, 2) void gemm_mfma2_kernel(
        const float* __restrict__ A, const unsigned short* __restrict__ Wt,
        const void* __restrict__ bias, size_t bOff,
        float* __restrict__ C, int N, int K, const int* __restrict__ flag) {
    gemm_mfma_body<2>(A, Wt, bias, bOff, C, N, K, flag);
}

// ---------------------------------------------------------------------------
// Projector (unchanged).
// ---------------------------------------------------------------------------
__global__ __launch_bounds__(256) void proj_kernel(
        const void* __restrict__ hist, const void* __restrict__ pW1,
        const void* __restrict__ pb1,  const void* __restrict__ pW2,
        const void* __restrict__ pb2,  float* __restrict__ Xc,
        size_t m0, const int* __restrict__ flag) {
    const bool isb = (*flag != 0);
    __shared__ float h1[HP_];
    __shared__ float hrow[IN_];
    size_t m = blockIdx.x;
    size_t gm = m0 + m;
    int tid = threadIdx.x;
    if (tid < IN_) hrow[tid] = load1(hist, gm * IN_ + tid, isb);
    __syncthreads();
    if (tid < HP_) {
        float acc = 0.f;
        #pragma unroll
        for (int i = 0; i < IN_; ++i)
            acc = fmaf(hrow[i], load1(pW1, (size_t)i * HP_ + tid, isb), acc);
        acc += load1(pb1, tid, isb);
        h1[tid] = 0.5f * acc * (1.0f + erff(acc * 0.70710678118654752440f));
    }
    __syncthreads();
    for (int e = tid; e < E_; e += 256) {
        float acc = 0.f;
        #pragma unroll 8
        for (int i = 0; i < HP_; ++i)
            acc = fmaf(h1[i], load1(pW2, (size_t)i * E_ + e, isb), acc);
        acc += load1(pb2, e, isb);
        Xc[m * E_ + e] = acc;
    }
}

// ---------------------------------------------------------------------------
// LayerNorm (unchanged).
// ---------------------------------------------------------------------------
__device__ __forceinline__ float block_sum(float v, float* smem, int tid) {
    #pragma unroll
    for (int off = 32; off > 0; off >>= 1) v += __shfl_down(v, off, 64);
    __syncthreads();
    if ((tid & 63) == 0) smem[tid >> 6] = v;
    __syncthreads();
    if (tid == 0) smem[4] = smem[0] + smem[1] + smem[2] + smem[3];
    __syncthreads();
    return smem[4];
}

__global__ __launch_bounds__(256) void ln_kernel(float* __restrict__ Y,
        const void* __restrict__ g, size_t gOff,
        const void* __restrict__ b, size_t bOff,
        int N, const int* __restrict__ flag) {
    const bool isb = (*flag != 0);
    __shared__ float smem[5];
    size_t row = blockIdx.x;
    float* y = Y + row * (size_t)N;
    int tid = threadIdx.x;
    int nPer = N >> 8;
    float vals[4];
    float s = 0.f;
    for (int i = 0; i < nPer; ++i) { float v = y[tid + (i << 8)]; vals[i] = v; s += v; }
    float mean = block_sum(s, smem, tid) / (float)N;
    float sq = 0.f;
    for (int i = 0; i < nPer; ++i) { float d0 = vals[i] - mean; sq += d0 * d0; }
    float var = block_sum(sq, smem, tid) / (float)N;
    float denom = sqrtf(var + 1e-5f);
    for (int i = 0; i < nPer; ++i) {
        int c = tid + (i << 8);
        y[c] = (vals[i] - mean) / denom * load1(g, gOff + c, isb) + load1(b, bOff + c, isb);
    }
}

// ---------------------------------------------------------------------------
// LIF kernels (unchanged).
// ---------------------------------------------------------------------------
__global__ __launch_bounds__(256) void lif_kernel(float* __restrict__ Y, int N) {
    int f = blockIdx.x * 256 + threadIdx.x;
    int b = blockIdx.y;
    size_t base = (size_t)b * T_ * N + f;
    float v = 0.f;
    for (int t = 0; t < T_; ++t) {
        size_t idx = base + (size_t)t * N;
        float x = Y[idx];
        v = v + (x - v) * 0.5f;
        float s = (v - 1.0f >= 0.0f) ? 1.0f : 0.0f;
        v = v * (1.0f - s);
        Y[idx] = s;
    }
}

__global__ __launch_bounds__(256) void lif_add_kernel(const float* __restrict__ Z,
                                                      float* __restrict__ Xc) {
    int e = blockIdx.x * 256 + threadIdx.x;
    int b = blockIdx.y;
    size_t base = (size_t)b * T_ * E_ + e;
    float v = 0.f;
    for (int t = 0; t < T_; ++t) {
        size_t idx = base + (size_t)t * E_;
        float x = Z[idx];
        v = v + (x - v) * 0.5f;
        float s = (v - 1.0f >= 0.0f) ? 1.0f : 0.0f;
        v = v * (1.0f - s);
        Xc[idx] += s;
    }
}

__global__ void out_kernel(const float* __restrict__ Xc, void* __restrict__ out,
                           int b0, const int* __restrict__ flag) {
    int i = blockIdx.x * 256 + threadIdx.x;
    int bl = i / E_, e = i - bl * E_;
    float v = Xc[((size_t)bl * T_ + (T_ - 1)) * E_ + e];
    size_t oi = (size_t)(b0 + bl) * E_ + e;
    if (*flag) ((bf16*)out)[oi] = __float2bfloat16(v);
    else       ((float*)out)[oi] = v;
}

// ---------------------------------------------------------------------------
extern "C" void kernel_launch(void* const* d_in, const int* in_sizes, int n_in,
                              void* d_out, int out_size, void* d_ws, size_t ws_size,
                              hipStream_t stream) {
    char* ws = (char*)d_ws;
    int* flag = (int*)ws;

    // Wt area: per matrix 3*K*N ushorts; 8 matrices (4 layers x 2).
    const size_t wtCount = 3 * (size_t)E_ * H_;
    const size_t wtBytes = 2 * D_ * wtCount * sizeof(unsigned short); // ~25.2 MB
    unsigned short* Wt1 = (unsigned short*)(ws + 256);
    unsigned short* Wt2 = Wt1 + (size_t)D_ * wtCount;

    size_t used = 256 + wtBytes;
    size_t avail = (ws_size > used) ? ws_size - used : 0;
    int CB = 256;
    while (CB > 1 && (size_t)CB * T_ * (size_t)(E_ + H_ + E_) * 4 > avail) CB >>= 1;
    const int R = CB * T_;

    float* Xc  = (float*)(ws + used);
    float* HBc = Xc + (size_t)R * E_;
    float* Y2c = HBc + (size_t)R * H_;

    sniff_kernel<<<1, 256, 0, stream>>>((const unsigned short*)d_in[0], flag);

    // Precompute transposed+split weights once.
    for (int d = 0; d < D_; ++d) {
        wsplit_kernel<<<dim3(H_ / 32, E_ / 32), 256, 0, stream>>>(
            d_in[5], (size_t)d * E_ * H_, Wt1 + (size_t)d * wtCount, E_, H_, flag);
        wsplit_kernel<<<dim3(E_ / 32, H_ / 32), 256, 0, stream>>>(
            d_in[9], (size_t)d * H_ * E_, Wt2 + (size_t)d * wtCount, H_, E_, flag);
    }

    for (int b0 = 0; b0 < B_; b0 += CB) {
        proj_kernel<<<R, 256, 0, stream>>>(d_in[0], d_in[1], d_in[2], d_in[3],
                                           d_in[4], Xc, (size_t)b0 * T_, flag);
        for (int d = 0; d < D_; ++d) {
            size_t b1o = (size_t)d * H_;
            size_t b2o = (size_t)d * E_;

            gemm_mfma3_kernel<<<dim3(H_ / 128, R / 128), 256, 0, stream>>>(
                Xc, Wt1 + (size_t)d * wtCount, d_in[6], b1o, HBc, H_, E_, flag);
            ln_kernel<<<R, 256, 0, stream>>>(HBc, d_in[7], b1o, d_in[8], b1o, H_, flag);
            lif_kernel<<<dim3(H_ / 256, CB), 256, 0, stream>>>(HBc, H_);

            gemm_mfma2_kernel<<<dim3(E_ / 128, R / 128), 256, 0, stream>>>(
                HBc, Wt2 + (size_t)d * wtCount, d_in[10], b2o, Y2c, E_, H_, flag);
            ln_kernel<<<R, 256, 0, stream>>>(Y2c, d_in[11], b2o, d_in[12], b2o, E_, flag);
            lif_add_kernel<<<dim3(E_ / 256, CB), 256, 0, stream>>>(Y2c, Xc);
        }
        out_kernel<<<(CB * E_) / 256, 256, 0, stream>>>(Xc, d_out, b0, flag);
    }
}

// Round 7
// 4347.703 us; speedup vs baseline: 2.3216x; 1.1924x over previous
//
#include <hip/hip_runtime.h>
#include <hip/hip_bf16.h>
#include <math.h>

#define B_  256
#define T_  256
#define IN_ 4
#define HP_ 64
#define E_  512
#define H_  1024
#define D_  4

typedef __hip_bfloat16 bf16;
typedef _Float16 f16;
typedef _Float16 f16x8 __attribute__((ext_vector_type(8)));
typedef float f32x4 __attribute__((ext_vector_type(4)));

// ---------------------------------------------------------------------------
// Dual-dtype load helpers: flag!=0 -> input arrays are bf16, else fp32.
// ---------------------------------------------------------------------------
__device__ __forceinline__ float load1(const void* p, size_t idx, bool isb) {
    if (isb) {
        unsigned int u = ((const unsigned short*)p)[idx];
        return __uint_as_float(u << 16);
    }
    return ((const float*)p)[idx];
}

__device__ __forceinline__ float4 load4(const void* p, size_t idx, bool isb) {
    if (isb) {
        ushort4 u = *(const ushort4*)((const unsigned short*)p + idx);
        float4 r;
        r.x = __uint_as_float(((unsigned int)u.x) << 16);
        r.y = __uint_as_float(((unsigned int)u.y) << 16);
        r.z = __uint_as_float(((unsigned int)u.z) << 16);
        r.w = __uint_as_float(((unsigned int)u.w) << 16);
        return r;
    }
    return *((const float4*)p + (idx >> 2));
}

// ---------------------------------------------------------------------------
// Exact 3-plane f16 split:  x ~= h + lb*2^-11   (lo stored pre-scaled by 2^11
// so it never hits f16 subnormal flush; hs = h*2^-11 is the matching partner)
// x*w = h*wh + (h*2^-11)*(wl*2^11) + (l*2^11)*(wh*2^-11)   [all exact terms]
// ---------------------------------------------------------------------------
__device__ __forceinline__ void split3(float x, f16& h, f16& hs, f16& lb) {
    h = (f16)x;
    float hf = (float)h;
    hs = (f16)(hf * 4.8828125e-4f);        // *2^-11, exact exponent shift
    lb = (f16)((x - hf) * 2048.0f);        // residual, pre-scaled *2^11
}

// ---------------------------------------------------------------------------
// Dtype sniff (unchanged).
// ---------------------------------------------------------------------------
__global__ void sniff_kernel(const unsigned short* __restrict__ p,
                             int* __restrict__ flag) {
    __shared__ int cnt;
    if (threadIdx.x == 0) cnt = 0;
    __syncthreads();
    int local = 0;
    for (int i = threadIdx.x; i < 65536; i += blockDim.x) {
        unsigned int bits = ((unsigned int)p[i]) << 16;
        float v = __uint_as_float(bits);
        float a = fabsf(v);
        if (!(a <= 1e4f)) local++;
        else if (v != 0.0f && a < 1e-6f) local++;
    }
    atomicAdd(&cnt, local);
    __syncthreads();
    if (threadIdx.x == 0) *flag = (cnt > 1024) ? 0 : 1;
}

// ---------------------------------------------------------------------------
// Weight transpose+split: W[K][N] (fp32/bf16) -> Wt ushort[N][3K]:
// per n-row: [hi(k=0..K-1) | hi*2^-11 | lo*2^11]  (f16 bit patterns).
// ---------------------------------------------------------------------------
__global__ __launch_bounds__(256) void wsplit_kernel(
        const void* __restrict__ W, size_t wOff, unsigned short* __restrict__ Wt,
        int K, int N, const int* __restrict__ flag) {
    const bool isb = (*flag != 0);
    __shared__ float tile[32][33];
    const int n0 = blockIdx.x * 32, k0 = blockIdx.y * 32;
    const int t = threadIdx.x;
    {
        int lk = t >> 3, ln0 = (t & 7) << 2;
        float4 v = load4(W, wOff + (size_t)(k0 + lk) * N + n0 + ln0, isb);
        tile[lk][ln0 + 0] = v.x; tile[lk][ln0 + 1] = v.y;
        tile[lk][ln0 + 2] = v.z; tile[lk][ln0 + 3] = v.w;
    }
    __syncthreads();
    int n = t >> 3, kq0 = (t & 7) << 2;
    size_t base = (size_t)(n0 + n) * (3 * (size_t)K) + k0 + kq0;
    #pragma unroll
    for (int j = 0; j < 4; ++j) {
        float x = tile[kq0 + j][n];
        f16 h, hs, lb;
        split3(x, h, hs, lb);
        Wt[base + j]         = *(unsigned short*)&h;
        Wt[base + j + K]     = *(unsigned short*)&hs;
        Wt[base + j + 2 * K] = *(unsigned short*)&lb;
    }
}

// ---------------------------------------------------------------------------
// MFMA GEMM (unchanged from R6): 128x128 tile, BK=32, 4 waves 2x2,
// wave-tile 64x64, mfma_f32_16x16x32_f16, 3-plane (or 2-plane for {0,1}
// spike inputs) exact f16 split. XOR-swizzled LDS slots.
// ---------------------------------------------------------------------------
template<int NPL>
__device__ __forceinline__ void gemm_mfma_body(
        const float* __restrict__ A, const unsigned short* __restrict__ Wt,
        const void* __restrict__ bias, size_t bOff,
        float* __restrict__ C, int N, int K, const int* __restrict__ flag) {
    const bool isb = (*flag != 0);
    __shared__ unsigned short As[128 * 128];   // 32 KB
    __shared__ unsigned short Bs[128 * 128];   // 32 KB
    const int bn = blockIdx.x * 128;
    const int bm = blockIdx.y * 128;
    const int tid  = threadIdx.x;
    const int lane = tid & 63;
    const int wave = tid >> 6;
    const int wm = wave >> 1;
    const int wn = wave & 1;
    const int g  = lane >> 4;
    const int lr = lane & 15;

    const int sar = tid >> 1;
    const int sah = tid & 1;
    const int sbn = tid >> 1;
    const int sq  = tid & 1;

    const int NB = (NPL == 3) ? 3 : 2;
    const int BPL[3] = {0, (NPL == 3) ? 1 : 2, 2};

    f32x4 acc[4][4];
    #pragma unroll
    for (int i = 0; i < 4; ++i)
        #pragma unroll
        for (int j = 0; j < 4; ++j) acc[i][j] = (f32x4){0.f, 0.f, 0.f, 0.f};

    const float* Ap = A + (size_t)(bm + sar) * K + sah * 16;
    const unsigned short* Wp = Wt + (size_t)(bn + sbn) * (3 * (size_t)K) + sq * 16;

    float x[16];
    f16x8 wv[6];
    #pragma unroll
    for (int c = 0; c < 4; ++c) {
        float4 v = *(const float4*)(Ap + c * 4);
        x[c * 4 + 0] = v.x; x[c * 4 + 1] = v.y;
        x[c * 4 + 2] = v.z; x[c * 4 + 3] = v.w;
    }
    #pragma unroll
    for (int pi = 0; pi < NB; ++pi)
        #pragma unroll
        for (int c = 0; c < 2; ++c)
            wv[pi * 2 + c] = *(const f16x8*)(Wp + (size_t)BPL[pi] * K + c * 8);

    const int nt = K >> 5;
    for (int t = 0; t < nt; ++t) {
        const int arb = sar * 128, asw = sar & 7;
        #pragma unroll
        for (int c = 0; c < 2; ++c) {
            f16x8 h8, s8, l8;
            #pragma unroll
            for (int j = 0; j < 8; ++j) {
                f16 h, hs, lb;
                split3(x[c * 8 + j], h, hs, lb);
                h8[j] = h; s8[j] = hs; l8[j] = lb;
            }
            const int gg = sah * 2 + c;
            *(f16x8*)&As[arb + (((0 << 2) | gg) ^ asw) * 8] = h8;
            *(f16x8*)&As[arb + (((1 << 2) | gg) ^ asw) * 8] = s8;
            if (NPL == 3)
                *(f16x8*)&As[arb + (((2 << 2) | gg) ^ asw) * 8] = l8;
        }
        const int brb = sbn * 128, bsw = sbn & 7;
        #pragma unroll
        for (int pi = 0; pi < NB; ++pi)
            #pragma unroll
            for (int c = 0; c < 2; ++c)
                *(f16x8*)&Bs[brb + (((BPL[pi] << 2) | (sq * 2 + c)) ^ bsw) * 8]
                    = wv[pi * 2 + c];
        __syncthreads();
        if (t + 1 < nt) {
            const int k0 = (t + 1) << 5;
            #pragma unroll
            for (int c = 0; c < 4; ++c) {
                float4 v = *(const float4*)(Ap + k0 + c * 4);
                x[c * 4 + 0] = v.x; x[c * 4 + 1] = v.y;
                x[c * 4 + 2] = v.z; x[c * 4 + 3] = v.w;
            }
            #pragma unroll
            for (int pi = 0; pi < NB; ++pi)
                #pragma unroll
                for (int c = 0; c < 2; ++c)
                    wv[pi * 2 + c] =
                        *(const f16x8*)(Wp + (size_t)BPL[pi] * K + k0 + c * 8);
        }
        #pragma unroll
        for (int p = 0; p < NPL; ++p) {
            const int pa = p;
            const int pb = (p == 0) ? 0 : ((p == 1) ? 2 : 1);
            f16x8 af[4], bf[4];
            #pragma unroll
            for (int mi = 0; mi < 4; ++mi) {
                const int ar = wm * 64 + mi * 16 + lr;
                af[mi] = *(const f16x8*)&As[ar * 128 + (((pa << 2) | g) ^ (ar & 7)) * 8];
            }
            #pragma unroll
            for (int ni = 0; ni < 4; ++ni) {
                const int br = wn * 64 + ni * 16 + lr;
                bf[ni] = *(const f16x8*)&Bs[br * 128 + (((pb << 2) | g) ^ (br & 7)) * 8];
            }
            #pragma unroll
            for (int mi = 0; mi < 4; ++mi)
                #pragma unroll
                for (int ni = 0; ni < 4; ++ni)
                    acc[mi][ni] = __builtin_amdgcn_mfma_f32_16x16x32_f16(
                        af[mi], bf[ni], acc[mi][ni], 0, 0, 0);
        }
        __syncthreads();
    }
    #pragma unroll
    for (int ni = 0; ni < 4; ++ni) {
        const int col = bn + wn * 64 + ni * 16 + lr;
        const float bv = load1(bias, bOff + col, isb);
        #pragma unroll
        for (int mi = 0; mi < 4; ++mi) {
            #pragma unroll
            for (int r = 0; r < 4; ++r) {
                const size_t row = (size_t)(bm + wm * 64 + mi * 16 + g * 4 + r);
                C[row * N + col] = acc[mi][ni][r] + bv;
            }
        }
    }
}

__global__ __launch_bounds__(256, 2) void gemm_mfma3_kernel(
        const float* __restrict__ A, const unsigned short* __restrict__ Wt,
        const void* __restrict__ bias, size_t bOff,
        float* __restrict__ C, int N, int K, const int* __restrict__ flag) {
    gemm_mfma_body<3>(A, Wt, bias, bOff, C, N, K, flag);
}

__global__ __launch_bounds__(256, 2) void gemm_mfma2_kernel(
        const float* __restrict__ A, const unsigned short* __restrict__ Wt,
        const void* __restrict__ bias, size_t bOff,
        float* __restrict__ C, int N, int K, const int* __restrict__ flag) {
    gemm_mfma_body<2>(A, Wt, bias, bOff, C, N, K, flag);
}

// ---------------------------------------------------------------------------
// Projector v2: 16 rows per block (pW2 re-read 16x less often).
// Per-element arithmetic identical to v1: h1 = gelu(sum_i fmaf asc + pb1);
// out = sum_i fmaf(h1[i], pW2[i*E+e]) asc + pb2[e].
// ---------------------------------------------------------------------------
#define RB_ 16
__global__ __launch_bounds__(256) void proj_kernel(
        const void* __restrict__ hist, const void* __restrict__ pW1,
        const void* __restrict__ pb1,  const void* __restrict__ pW2,
        const void* __restrict__ pb2,  float* __restrict__ Xc,
        size_t m0, const int* __restrict__ flag) {
    const bool isb = (*flag != 0);
    __shared__ float h1[RB_][HP_];
    const size_t mb = (size_t)blockIdx.x * RB_;     // chunk-local row base
    const int tid = threadIdx.x;
    #pragma unroll
    for (int rep = 0; rep < 4; ++rep) {
        int idx = tid + rep * 256;       // 0..1023 = 16 rows x 64 cols
        int r = idx >> 6, c = idx & 63;
        size_t gm = m0 + mb + r;
        float acc = 0.f;
        #pragma unroll
        for (int i = 0; i < IN_; ++i)
            acc = fmaf(load1(hist, gm * IN_ + i, isb),
                       load1(pW1, (size_t)i * HP_ + c, isb), acc);
        acc += load1(pb1, c, isb);
        // exact GELU: 0.5*x*(1+erf(x/sqrt(2)))
        h1[r][c] = 0.5f * acc * (1.0f + erff(acc * 0.70710678118654752440f));
    }
    __syncthreads();
    for (int r = 0; r < RB_; ++r) {
        #pragma unroll
        for (int half = 0; half < 2; ++half) {
            int e = tid + half * 256;
            float acc = 0.f;
            #pragma unroll 8
            for (int i = 0; i < HP_; ++i)
                acc = fmaf(h1[r][i], load1(pW2, (size_t)i * E_ + e, isb), acc);
            acc += load1(pb2, e, isb);
            Xc[(mb + r) * E_ + e] = acc;
        }
    }
}

// ---------------------------------------------------------------------------
// LayerNorm (unchanged — bit-identical reduction order preserved).
// ---------------------------------------------------------------------------
__device__ __forceinline__ float block_sum(float v, float* smem, int tid) {
    #pragma unroll
    for (int off = 32; off > 0; off >>= 1) v += __shfl_down(v, off, 64);
    __syncthreads();
    if ((tid & 63) == 0) smem[tid >> 6] = v;
    __syncthreads();
    if (tid == 0) smem[4] = smem[0] + smem[1] + smem[2] + smem[3];
    __syncthreads();
    return smem[4];
}

__global__ __launch_bounds__(256) void ln_kernel(float* __restrict__ Y,
        const void* __restrict__ g, size_t gOff,
        const void* __restrict__ b, size_t bOff,
        int N, const int* __restrict__ flag) {
    const bool isb = (*flag != 0);
    __shared__ float smem[5];
    size_t row = blockIdx.x;
    float* y = Y + row * (size_t)N;
    int tid = threadIdx.x;
    int nPer = N >> 8;
    float vals[4];
    float s = 0.f;
    for (int i = 0; i < nPer; ++i) { float v = y[tid + (i << 8)]; vals[i] = v; s += v; }
    float mean = block_sum(s, smem, tid) / (float)N;
    float sq = 0.f;
    for (int i = 0; i < nPer; ++i) { float d0 = vals[i] - mean; sq += d0 * d0; }
    float var = block_sum(sq, smem, tid) / (float)N;
    float denom = sqrtf(var + 1e-5f);
    for (int i = 0; i < nPer; ++i) {
        int c = tid + (i << 8);
        y[c] = (vals[i] - mean) / denom * load1(g, gOff + c, isb) + load1(b, bOff + c, isb);
    }
}

// ---------------------------------------------------------------------------
// LIF scan, software-pipelined: unroll t by 8 -> 8 independent loads issued
// together, then 8 dependent v-updates, then 8 stores. Per-element op
// sequence identical to the scalar loop (bit-identical). 64-thread blocks
// spread waves across all CUs.
// ---------------------------------------------------------------------------
__global__ __launch_bounds__(64) void lif_kernel(float* __restrict__ Y, int N) {
    int f = blockIdx.x * 64 + threadIdx.x;
    int b = blockIdx.y;
    size_t base = (size_t)b * T_ * N + f;
    float v = 0.f;
    for (int t0 = 0; t0 < T_; t0 += 8) {
        float x[8], s[8];
        #pragma unroll
        for (int j = 0; j < 8; ++j) x[j] = Y[base + (size_t)(t0 + j) * N];
        #pragma unroll
        for (int j = 0; j < 8; ++j) {
            v = v + (x[j] - v) * 0.5f;
            s[j] = (v - 1.0f >= 0.0f) ? 1.0f : 0.0f;
            v = v * (1.0f - s[j]);
        }
        #pragma unroll
        for (int j = 0; j < 8; ++j) Y[base + (size_t)(t0 + j) * N] = s[j];
    }
}

// Second LIF fused with residual add into Xc, same pipelining.
__global__ __launch_bounds__(64) void lif_add_kernel(const float* __restrict__ Z,
                                                     float* __restrict__ Xc) {
    int e = blockIdx.x * 64 + threadIdx.x;
    int b = blockIdx.y;
    size_t base = (size_t)b * T_ * E_ + e;
    float v = 0.f;
    for (int t0 = 0; t0 < T_; t0 += 8) {
        float x[8], xc[8], s[8];
        #pragma unroll
        for (int j = 0; j < 8; ++j) x[j]  = Z[base + (size_t)(t0 + j) * E_];
        #pragma unroll
        for (int j = 0; j < 8; ++j) xc[j] = Xc[base + (size_t)(t0 + j) * E_];
        #pragma unroll
        for (int j = 0; j < 8; ++j) {
            v = v + (x[j] - v) * 0.5f;
            s[j] = (v - 1.0f >= 0.0f) ? 1.0f : 0.0f;
            v = v * (1.0f - s[j]);
        }
        #pragma unroll
        for (int j = 0; j < 8; ++j)
            Xc[base + (size_t)(t0 + j) * E_] = xc[j] + s[j];
    }
}

__global__ void out_kernel(const float* __restrict__ Xc, void* __restrict__ out,
                           int b0, const int* __restrict__ flag) {
    int i = blockIdx.x * 256 + threadIdx.x;
    int bl = i / E_, e = i - bl * E_;
    float v = Xc[((size_t)bl * T_ + (T_ - 1)) * E_ + e];
    size_t oi = (size_t)(b0 + bl) * E_ + e;
    if (*flag) ((bf16*)out)[oi] = __float2bfloat16(v);
    else       ((float*)out)[oi] = v;
}

// ---------------------------------------------------------------------------
extern "C" void kernel_launch(void* const* d_in, const int* in_sizes, int n_in,
                              void* d_out, int out_size, void* d_ws, size_t ws_size,
                              hipStream_t stream) {
    char* ws = (char*)d_ws;
    int* flag = (int*)ws;

    // Wt area: per matrix 3*K*N ushorts; 8 matrices (4 layers x 2).
    const size_t wtCount = 3 * (size_t)E_ * H_;
    const size_t wtBytes = 2 * D_ * wtCount * sizeof(unsigned short); // ~25.2 MB
    unsigned short* Wt1 = (unsigned short*)(ws + 256);
    unsigned short* Wt2 = Wt1 + (size_t)D_ * wtCount;

    size_t used = 256 + wtBytes;
    size_t avail = (ws_size > used) ? ws_size - used : 0;
    int CB = 256;
    while (CB > 1 && (size_t)CB * T_ * (size_t)(E_ + H_ + E_) * 4 > avail) CB >>= 1;
    const int R = CB * T_;

    float* Xc  = (float*)(ws + used);
    float* HBc = Xc + (size_t)R * E_;
    float* Y2c = HBc + (size_t)R * H_;

    sniff_kernel<<<1, 256, 0, stream>>>((const unsigned short*)d_in[0], flag);

    // Precompute transposed+split weights once.
    for (int d = 0; d < D_; ++d) {
        wsplit_kernel<<<dim3(H_ / 32, E_ / 32), 256, 0, stream>>>(
            d_in[5], (size_t)d * E_ * H_, Wt1 + (size_t)d * wtCount, E_, H_, flag);
        wsplit_kernel<<<dim3(E_ / 32, H_ / 32), 256, 0, stream>>>(
            d_in[9], (size_t)d * H_ * E_, Wt2 + (size_t)d * wtCount, H_, E_, flag);
    }

    for (int b0 = 0; b0 < B_; b0 += CB) {
        proj_kernel<<<R / RB_, 256, 0, stream>>>(d_in[0], d_in[1], d_in[2], d_in[3],
                                                 d_in[4], Xc, (size_t)b0 * T_, flag);
        for (int d = 0; d < D_; ++d) {
            size_t b1o = (size_t)d * H_;
            size_t b2o = (size_t)d * E_;

            gemm_mfma3_kernel<<<dim3(H_ / 128, R / 128), 256, 0, stream>>>(
                Xc, Wt1 + (size_t)d * wtCount, d_in[6], b1o, HBc, H_, E_, flag);
            ln_kernel<<<R, 256, 0, stream>>>(HBc, d_in[7], b1o, d_in[8], b1o, H_, flag);
            lif_kernel<<<dim3(H_ / 64, CB), 64, 0, stream>>>(HBc, H_);

            gemm_mfma2_kernel<<<dim3(E_ / 128, R / 128), 256, 0, stream>>>(
                HBc, Wt2 + (size_t)d * wtCount, d_in[10], b2o, Y2c, E_, H_, flag);
            ln_kernel<<<R, 256, 0, stream>>>(Y2c, d_in[11], b2o, d_in[12], b2o, E_, flag);
            lif_add_kernel<<<dim3(E_ / 64, CB), 64, 0, stream>>>(Y2c, Xc);
        }
        out_kernel<<<(CB * E_) / 256, 256, 0, stream>>>(Xc, d_out, b0, flag);
    }
}

// Round 8
// 3720.733 us; speedup vs baseline: 2.7128x; 1.1685x over previous
//
#include <hip/hip_runtime.h>
#include <hip/hip_bf16.h>
#include <math.h>

#define B_  256
#define T_  256
#define IN_ 4
#define HP_ 64
#define E_  512
#define H_  1024
#define D_  4

typedef __hip_bfloat16 bf16;
typedef _Float16 f16;
typedef _Float16 f16x8 __attribute__((ext_vector_type(8)));
typedef float f32x4 __attribute__((ext_vector_type(4)));

// ---------------------------------------------------------------------------
// Dual-dtype load helpers: flag!=0 -> input arrays are bf16, else fp32.
// ---------------------------------------------------------------------------
__device__ __forceinline__ float load1(const void* p, size_t idx, bool isb) {
    if (isb) {
        unsigned int u = ((const unsigned short*)p)[idx];
        return __uint_as_float(u << 16);
    }
    return ((const float*)p)[idx];
}

__device__ __forceinline__ float4 load4(const void* p, size_t idx, bool isb) {
    if (isb) {
        ushort4 u = *(const ushort4*)((const unsigned short*)p + idx);
        float4 r;
        r.x = __uint_as_float(((unsigned int)u.x) << 16);
        r.y = __uint_as_float(((unsigned int)u.y) << 16);
        r.z = __uint_as_float(((unsigned int)u.z) << 16);
        r.w = __uint_as_float(((unsigned int)u.w) << 16);
        return r;
    }
    return *((const float4*)p + (idx >> 2));
}

// ---------------------------------------------------------------------------
// Exact 3-plane f16 split:  x ~= h + lb*2^-11  (lb pre-scaled by 2^11).
// x*w = h*wh + (h*2^-11)*(wl*2^11) + (l*2^11)*(wh*2^-11)   [exact terms]
// The *2^-11 partner planes are derived in-register (exact pow2 scale).
// ---------------------------------------------------------------------------
__device__ __forceinline__ void split3(float x, f16& h, f16& hs, f16& lb) {
    h = (f16)x;
    float hf = (float)h;
    hs = (f16)(hf * 4.8828125e-4f);        // *2^-11 (kept for reference)
    lb = (f16)((x - hf) * 2048.0f);        // residual, pre-scaled *2^11
}

// ---------------------------------------------------------------------------
// Dtype sniff (unchanged).
// ---------------------------------------------------------------------------
__global__ void sniff_kernel(const unsigned short* __restrict__ p,
                             int* __restrict__ flag) {
    __shared__ int cnt;
    if (threadIdx.x == 0) cnt = 0;
    __syncthreads();
    int local = 0;
    for (int i = threadIdx.x; i < 65536; i += blockDim.x) {
        unsigned int bits = ((unsigned int)p[i]) << 16;
        float v = __uint_as_float(bits);
        float a = fabsf(v);
        if (!(a <= 1e4f)) local++;
        else if (v != 0.0f && a < 1e-6f) local++;
    }
    atomicAdd(&cnt, local);
    __syncthreads();
    if (threadIdx.x == 0) *flag = (cnt > 1024) ? 0 : 1;
}

// ---------------------------------------------------------------------------
// Weight transpose+split: W[K][N] -> Wt ushort[N][2K]: [h(k=0..K-1) | lb].
// (hs plane is derived in the GEMM: exact h * 2^-11.)
// ---------------------------------------------------------------------------
__global__ __launch_bounds__(256) void wsplit_kernel(
        const void* __restrict__ W, size_t wOff, unsigned short* __restrict__ Wt,
        int K, int N, const int* __restrict__ flag) {
    const bool isb = (*flag != 0);
    __shared__ float tile[32][33];
    const int n0 = blockIdx.x * 32, k0 = blockIdx.y * 32;
    const int t = threadIdx.x;
    {
        int lk = t >> 3, ln0 = (t & 7) << 2;
        float4 v = load4(W, wOff + (size_t)(k0 + lk) * N + n0 + ln0, isb);
        tile[lk][ln0 + 0] = v.x; tile[lk][ln0 + 1] = v.y;
        tile[lk][ln0 + 2] = v.z; tile[lk][ln0 + 3] = v.w;
    }
    __syncthreads();
    int n = t >> 3, kq0 = (t & 7) << 2;
    size_t base = (size_t)(n0 + n) * (2 * (size_t)K) + k0 + kq0;
    #pragma unroll
    for (int j = 0; j < 4; ++j) {
        float x = tile[kq0 + j][n];
        f16 h, hs, lb;
        split3(x, h, hs, lb);
        Wt[base + j]     = *(unsigned short*)&h;
        Wt[base + j + K] = *(unsigned short*)&lb;
    }
}

// ---------------------------------------------------------------------------
// MFMA GEMM: C[M,N] = A @ W + bias.  A is PRE-SPLIT f16 planes:
//   NPL=3: At[row][2K] = {h, lb}  (full fp32 precision, 3 product planes)
//   NPL=2: At[row][K]  = {h}      (A is exact {0,1} spikes; 2 planes)
// Wt[n][2K] = {h, lb}.  hs planes derived in-reg: frag * 2^-11 (exact).
// tile 128x128, BK=32, 4 waves 2x2, wave-tile 64x64, mfma_f32_16x16x32_f16.
// LDS rows = 8 slots x 16B, slot (pl*4+g) ^ (row&7): staged writes spread
// evenly; frag reads 2-way max (free). 32 KB total -> 3 blocks/CU.
// Product planes accumulate p0,p1,p2 in the same order/values as R6 ->
// bit-identical output.
// ---------------------------------------------------------------------------
template<int NPL>
__device__ __forceinline__ void gemm_mfma_body(
        const unsigned short* __restrict__ At, const unsigned short* __restrict__ Wt,
        const void* __restrict__ bias, size_t bOff,
        float* __restrict__ C, int N, int K, const int* __restrict__ flag) {
    const bool isb = (*flag != 0);
    constexpr int APL = (NPL == 3) ? 2 : 1;      // stored A planes
    __shared__ unsigned short As[128 * 64];      // 16 KB
    __shared__ unsigned short Bs[128 * 64];      // 16 KB
    const int bn = blockIdx.x * 128;
    const int bm = blockIdx.y * 128;
    const int tid  = threadIdx.x;
    const int lane = tid & 63;
    const int wave = tid >> 6;
    const int wm = wave >> 1;
    const int wn = wave & 1;
    const int g  = lane >> 4;          // k-group 0..3
    const int lr = lane & 15;

    const int sar = tid >> 1;          // A row 0..127
    const int sah = tid & 1;           // A k-half
    const int sbn = tid >> 1;          // B n-row 0..127
    const int sq  = tid & 1;           // B k-half

    const f16 C11 = (f16)4.8828125e-4f;   // 2^-11
    const f16x8 c11v = {C11, C11, C11, C11, C11, C11, C11, C11};

    f32x4 acc[4][4];
    #pragma unroll
    for (int i = 0; i < 4; ++i)
        #pragma unroll
        for (int j = 0; j < 4; ++j) acc[i][j] = (f32x4){0.f, 0.f, 0.f, 0.f};

    const unsigned short* Ap = At + (size_t)(bm + sar) * (APL * (size_t)K) + sah * 16;
    const unsigned short* Wp = Wt + (size_t)(bn + sbn) * (2 * (size_t)K) + sq * 16;

    // prologue: prefetch tile 0
    f16x8 av[2 * APL], wv[4];
    #pragma unroll
    for (int pl = 0; pl < APL; ++pl)
        #pragma unroll
        for (int c = 0; c < 2; ++c)
            av[pl * 2 + c] = *(const f16x8*)(Ap + (size_t)pl * K + c * 8);
    #pragma unroll
    for (int pl = 0; pl < 2; ++pl)
        #pragma unroll
        for (int c = 0; c < 2; ++c)
            wv[pl * 2 + c] = *(const f16x8*)(Wp + (size_t)pl * K + c * 8);

    const int nt = K >> 5;
    for (int t = 0; t < nt; ++t) {
        // ---- store staged regs to LDS ----
        const int arb = sar * 64, asw = sar & 7;
        #pragma unroll
        for (int pl = 0; pl < APL; ++pl)
            #pragma unroll
            for (int c = 0; c < 2; ++c) {
                const int gg = sah * 2 + c;
                *(f16x8*)&As[arb + (((pl << 2) | gg) ^ asw) * 8] = av[pl * 2 + c];
            }
        const int brb = sbn * 64, bsw = sbn & 7;
        #pragma unroll
        for (int pl = 0; pl < 2; ++pl)
            #pragma unroll
            for (int c = 0; c < 2; ++c) {
                const int gg = sq * 2 + c;
                *(f16x8*)&Bs[brb + (((pl << 2) | gg) ^ bsw) * 8] = wv[pl * 2 + c];
            }
        __syncthreads();
        // ---- prefetch next tile ----
        if (t + 1 < nt) {
            const int k0 = (t + 1) << 5;
            #pragma unroll
            for (int pl = 0; pl < APL; ++pl)
                #pragma unroll
                for (int c = 0; c < 2; ++c)
                    av[pl * 2 + c] = *(const f16x8*)(Ap + (size_t)pl * K + k0 + c * 8);
            #pragma unroll
            for (int pl = 0; pl < 2; ++pl)
                #pragma unroll
                for (int c = 0; c < 2; ++c)
                    wv[pl * 2 + c] = *(const f16x8*)(Wp + (size_t)pl * K + k0 + c * 8);
        }
        // ---- fragments ----
        f16x8 a0[4], b0[4], b2[4], a2[4];
        #pragma unroll
        for (int mi = 0; mi < 4; ++mi) {
            const int ar = wm * 64 + mi * 16 + lr;
            a0[mi] = *(const f16x8*)&As[ar * 64 + ((g ^ (ar & 7))) * 8];
            if (NPL == 3)
                a2[mi] = *(const f16x8*)&As[ar * 64 + (((4 | g) ^ (ar & 7))) * 8];
        }
        #pragma unroll
        for (int ni = 0; ni < 4; ++ni) {
            const int br = wn * 64 + ni * 16 + lr;
            b0[ni] = *(const f16x8*)&Bs[br * 64 + ((g ^ (br & 7))) * 8];
            b2[ni] = *(const f16x8*)&Bs[br * 64 + (((4 | g) ^ (br & 7))) * 8];
        }
        // ---- p0: h*wh ----
        #pragma unroll
        for (int mi = 0; mi < 4; ++mi)
            #pragma unroll
            for (int ni = 0; ni < 4; ++ni)
                acc[mi][ni] = __builtin_amdgcn_mfma_f32_16x16x32_f16(
                    a0[mi], b0[ni], acc[mi][ni], 0, 0, 0);
        // ---- p1: (h*2^-11)*(wl*2^11) ----
        {
            f16x8 a1[4];
            #pragma unroll
            for (int mi = 0; mi < 4; ++mi) a1[mi] = a0[mi] * c11v;
            #pragma unroll
            for (int mi = 0; mi < 4; ++mi)
                #pragma unroll
                for (int ni = 0; ni < 4; ++ni)
                    acc[mi][ni] = __builtin_amdgcn_mfma_f32_16x16x32_f16(
                        a1[mi], b2[ni], acc[mi][ni], 0, 0, 0);
        }
        // ---- p2: (l*2^11)*(wh*2^-11) ----
        if (NPL == 3) {
            f16x8 b1[4];
            #pragma unroll
            for (int ni = 0; ni < 4; ++ni) b1[ni] = b0[ni] * c11v;
            #pragma unroll
            for (int mi = 0; mi < 4; ++mi)
                #pragma unroll
                for (int ni = 0; ni < 4; ++ni)
                    acc[mi][ni] = __builtin_amdgcn_mfma_f32_16x16x32_f16(
                        a2[mi], b1[ni], acc[mi][ni], 0, 0, 0);
        }
        __syncthreads();
    }
    // ---- epilogue: C/D map col=lane&15, row=(lane>>4)*4+reg ----
    #pragma unroll
    for (int ni = 0; ni < 4; ++ni) {
        const int col = bn + wn * 64 + ni * 16 + lr;
        const float bv = load1(bias, bOff + col, isb);
        #pragma unroll
        for (int mi = 0; mi < 4; ++mi) {
            #pragma unroll
            for (int r = 0; r < 4; ++r) {
                const size_t row = (size_t)(bm + wm * 64 + mi * 16 + g * 4 + r);
                C[row * N + col] = acc[mi][ni][r] + bv;
            }
        }
    }
}

__global__ __launch_bounds__(256, 3) void gemm_mfma3_kernel(
        const unsigned short* __restrict__ At, const unsigned short* __restrict__ Wt,
        const void* __restrict__ bias, size_t bOff,
        float* __restrict__ C, int N, int K, const int* __restrict__ flag) {
    gemm_mfma_body<3>(At, Wt, bias, bOff, C, N, K, flag);
}

__global__ __launch_bounds__(256, 3) void gemm_mfma2_kernel(
        const unsigned short* __restrict__ At, const unsigned short* __restrict__ Wt,
        const void* __restrict__ bias, size_t bOff,
        float* __restrict__ C, int N, int K, const int* __restrict__ flag) {
    gemm_mfma_body<2>(At, Wt, bias, bOff, C, N, K, flag);
}

// ---------------------------------------------------------------------------
// Projector v3: 16 rows/block; phase2 loop-swapped so each thread keeps a
// 4-row x 8-col register accumulator and pW2 is loaded ONCE per i (float4).
// Per-element fmaf chain (ascending i) + pb2 identical to v2. Also emits the
// f16 {h,lb} split of the output into At1 (split3 unchanged).
// ---------------------------------------------------------------------------
#define RB_ 16
__global__ __launch_bounds__(256) void proj_kernel(
        const void* __restrict__ hist, const void* __restrict__ pW1,
        const void* __restrict__ pb1,  const void* __restrict__ pW2,
        const void* __restrict__ pb2,  float* __restrict__ Xc,
        unsigned short* __restrict__ At1,
        size_t m0, const int* __restrict__ flag) {
    const bool isb = (*flag != 0);
    __shared__ float h1[RB_][HP_];
    const size_t mb = (size_t)blockIdx.x * RB_;
    const int tid = threadIdx.x;
    const int lane = tid & 63;
    const int grp = tid >> 6;          // wave id 0..3 -> rows grp*4..grp*4+3
    #pragma unroll
    for (int rep = 0; rep < 4; ++rep) {
        int idx = tid + rep * 256;
        int r = idx >> 6, c = idx & 63;
        size_t gm = m0 + mb + r;
        float acc = 0.f;
        #pragma unroll
        for (int i = 0; i < IN_; ++i)
            acc = fmaf(load1(hist, gm * IN_ + i, isb),
                       load1(pW1, (size_t)i * HP_ + c, isb), acc);
        acc += load1(pb1, c, isb);
        h1[r][c] = 0.5f * acc * (1.0f + erff(acc * 0.70710678118654752440f));
    }
    __syncthreads();
    const int e0 = lane * 8;
    float acc[4][8];
    #pragma unroll
    for (int r = 0; r < 4; ++r)
        #pragma unroll
        for (int j = 0; j < 8; ++j) acc[r][j] = 0.f;
    for (int i = 0; i < HP_; ++i) {
        float4 wA = load4(pW2, (size_t)i * E_ + e0, isb);
        float4 wB = load4(pW2, (size_t)i * E_ + e0 + 4, isb);
        float w[8] = {wA.x, wA.y, wA.z, wA.w, wB.x, wB.y, wB.z, wB.w};
        #pragma unroll
        for (int r = 0; r < 4; ++r) {
            float h = h1[grp * 4 + r][i];
            #pragma unroll
            for (int j = 0; j < 8; ++j) acc[r][j] = fmaf(h, w[j], acc[r][j]);
        }
    }
    #pragma unroll
    for (int r = 0; r < 4; ++r) {
        size_t row = mb + grp * 4 + r;
        float o[8];
        #pragma unroll
        for (int j = 0; j < 8; ++j)
            o[j] = acc[r][j] + load1(pb2, e0 + j, isb);
        *(float4*)(Xc + row * E_ + e0)     = (float4){o[0], o[1], o[2], o[3]};
        *(float4*)(Xc + row * E_ + e0 + 4) = (float4){o[4], o[5], o[6], o[7]};
        f16x8 hv, lv;
        #pragma unroll
        for (int j = 0; j < 8; ++j) {
            f16 h, hs, lb;
            split3(o[j], h, hs, lb);
            hv[j] = h; lv[j] = lb;
        }
        *(f16x8*)&At1[row * (2 * E_) + e0]      = hv;
        *(f16x8*)&At1[row * (2 * E_) + E_ + e0] = lv;
    }
}

// ---------------------------------------------------------------------------
// LayerNorm (unchanged — bit-identical reduction order preserved).
// ---------------------------------------------------------------------------
__device__ __forceinline__ float block_sum(float v, float* smem, int tid) {
    #pragma unroll
    for (int off = 32; off > 0; off >>= 1) v += __shfl_down(v, off, 64);
    __syncthreads();
    if ((tid & 63) == 0) smem[tid >> 6] = v;
    __syncthreads();
    if (tid == 0) smem[4] = smem[0] + smem[1] + smem[2] + smem[3];
    __syncthreads();
    return smem[4];
}

__global__ __launch_bounds__(256) void ln_kernel(float* __restrict__ Y,
        const void* __restrict__ g, size_t gOff,
        const void* __restrict__ b, size_t bOff,
        int N, const int* __restrict__ flag) {
    const bool isb = (*flag != 0);
    __shared__ float smem[5];
    size_t row = blockIdx.x;
    float* y = Y + row * (size_t)N;
    int tid = threadIdx.x;
    int nPer = N >> 8;
    float vals[4];
    float s = 0.f;
    for (int i = 0; i < nPer; ++i) { float v = y[tid + (i << 8)]; vals[i] = v; s += v; }
    float mean = block_sum(s, smem, tid) / (float)N;
    float sq = 0.f;
    for (int i = 0; i < nPer; ++i) { float d0 = vals[i] - mean; sq += d0 * d0; }
    float var = block_sum(sq, smem, tid) / (float)N;
    float denom = sqrtf(var + 1e-5f);
    for (int i = 0; i < nPer; ++i) {
        int c = tid + (i << 8);
        y[c] = (vals[i] - mean) / denom * load1(g, gOff + c, isb) + load1(b, bOff + c, isb);
    }
}

// ---------------------------------------------------------------------------
// LIF scan (software-pipelined x8). Writes spikes DIRECTLY as the f16 h-plane
// At2[row][N] ({0,1} exact in f16; hs derived in the GEMM). Y left untouched
// after read (nothing else reads the spike tensor).
// ---------------------------------------------------------------------------
__global__ __launch_bounds__(64) void lif_kernel(const float* __restrict__ Y,
                                                 unsigned short* __restrict__ At2,
                                                 int N) {
    int f = blockIdx.x * 64 + threadIdx.x;
    int b = blockIdx.y;
    size_t base = (size_t)b * T_ * N + f;
    float v = 0.f;
    for (int t0 = 0; t0 < T_; t0 += 8) {
        float x[8], s[8];
        #pragma unroll
        for (int j = 0; j < 8; ++j) x[j] = Y[base + (size_t)(t0 + j) * N];
        #pragma unroll
        for (int j = 0; j < 8; ++j) {
            v = v + (x[j] - v) * 0.5f;
            s[j] = (v - 1.0f >= 0.0f) ? 1.0f : 0.0f;
            v = v * (1.0f - s[j]);
        }
        #pragma unroll
        for (int j = 0; j < 8; ++j) {
            f16 h = (f16)s[j];
            At2[base + (size_t)(t0 + j) * N] = *(unsigned short*)&h;
        }
    }
}

// Second LIF fused with residual add into Xc; also emits {h,lb} split of the
// updated Xc into At1 (feeds next layer's GEMM1).
__global__ __launch_bounds__(64) void lif_add_kernel(const float* __restrict__ Z,
                                                     float* __restrict__ Xc,
                                                     unsigned short* __restrict__ At1) {
    int e = blockIdx.x * 64 + threadIdx.x;
    int b = blockIdx.y;
    size_t base  = (size_t)b * T_ * E_ + e;
    size_t base2 = (size_t)b * T_ * (2 * E_) + e;
    float v = 0.f;
    for (int t0 = 0; t0 < T_; t0 += 8) {
        float x[8], xc[8], s[8];
        #pragma unroll
        for (int j = 0; j < 8; ++j) x[j]  = Z[base + (size_t)(t0 + j) * E_];
        #pragma unroll
        for (int j = 0; j < 8; ++j) xc[j] = Xc[base + (size_t)(t0 + j) * E_];
        #pragma unroll
        for (int j = 0; j < 8; ++j) {
            v = v + (x[j] - v) * 0.5f;
            s[j] = (v - 1.0f >= 0.0f) ? 1.0f : 0.0f;
            v = v * (1.0f - s[j]);
        }
        #pragma unroll
        for (int j = 0; j < 8; ++j) {
            float nx = xc[j] + s[j];
            Xc[base + (size_t)(t0 + j) * E_] = nx;
            f16 h, hs, lb;
            split3(nx, h, hs, lb);
            At1[base2 + (size_t)(t0 + j) * (2 * E_)]      = *(unsigned short*)&h;
            At1[base2 + (size_t)(t0 + j) * (2 * E_) + E_] = *(unsigned short*)&lb;
        }
    }
}

__global__ void out_kernel(const float* __restrict__ Xc, void* __restrict__ out,
                           int b0, const int* __restrict__ flag) {
    int i = blockIdx.x * 256 + threadIdx.x;
    int bl = i / E_, e = i - bl * E_;
    float v = Xc[((size_t)bl * T_ + (T_ - 1)) * E_ + e];
    size_t oi = (size_t)(b0 + bl) * E_ + e;
    if (*flag) ((bf16*)out)[oi] = __float2bfloat16(v);
    else       ((float*)out)[oi] = v;
}

// ---------------------------------------------------------------------------
extern "C" void kernel_launch(void* const* d_in, const int* in_sizes, int n_in,
                              void* d_out, int out_size, void* d_ws, size_t ws_size,
                              hipStream_t stream) {
    char* ws = (char*)d_ws;
    int* flag = (int*)ws;

    // Wt area: per matrix 2*K*N ushorts (h,lb planes); 8 matrices.
    const size_t wtCount = 2 * (size_t)E_ * H_;
    const size_t wtBytes = 2 * D_ * wtCount * sizeof(unsigned short); // ~16.8 MB
    unsigned short* Wt1 = (unsigned short*)(ws + 256);
    unsigned short* Wt2 = Wt1 + (size_t)D_ * wtCount;

    size_t used = 256 + wtBytes;
    size_t avail = (ws_size > used) ? ws_size - used : 0;
    // per batch: fp32 bufs T*(E+H+E)*4 + At1 T*2E*2 + At2 T*H*2 = 3 MiB
    const size_t perBatch = (size_t)T_ * ((E_ + H_ + E_) * 4 + 2 * E_ * 2 + H_ * 2);
    int CB = 256;
    while (CB > 1 && (size_t)CB * perBatch > avail) CB >>= 1;
    const int R = CB * T_;

    float* Xc  = (float*)(ws + used);
    float* HBc = Xc + (size_t)R * E_;
    float* Y2c = HBc + (size_t)R * H_;
    unsigned short* At1 = (unsigned short*)(Y2c + (size_t)R * E_);
    unsigned short* At2 = At1 + (size_t)R * 2 * E_;

    sniff_kernel<<<1, 256, 0, stream>>>((const unsigned short*)d_in[0], flag);

    // Precompute transposed+split weights once.
    for (int d = 0; d < D_; ++d) {
        wsplit_kernel<<<dim3(H_ / 32, E_ / 32), 256, 0, stream>>>(
            d_in[5], (size_t)d * E_ * H_, Wt1 + (size_t)d * wtCount, E_, H_, flag);
        wsplit_kernel<<<dim3(E_ / 32, H_ / 32), 256, 0, stream>>>(
            d_in[9], (size_t)d * H_ * E_, Wt2 + (size_t)d * wtCount, H_, E_, flag);
    }

    for (int b0 = 0; b0 < B_; b0 += CB) {
        proj_kernel<<<R / RB_, 256, 0, stream>>>(d_in[0], d_in[1], d_in[2], d_in[3],
                                                 d_in[4], Xc, At1, (size_t)b0 * T_, flag);
        for (int d = 0; d < D_; ++d) {
            size_t b1o = (size_t)d * H_;
            size_t b2o = (size_t)d * E_;

            gemm_mfma3_kernel<<<dim3(H_ / 128, R / 128), 256, 0, stream>>>(
                At1, Wt1 + (size_t)d * wtCount, d_in[6], b1o, HBc, H_, E_, flag);
            ln_kernel<<<R, 256, 0, stream>>>(HBc, d_in[7], b1o, d_in[8], b1o, H_, flag);
            lif_kernel<<<dim3(H_ / 64, CB), 64, 0, stream>>>(HBc, At2, H_);

            gemm_mfma2_kernel<<<dim3(E_ / 128, R / 128), 256, 0, stream>>>(
                At2, Wt2 + (size_t)d * wtCount, d_in[10], b2o, Y2c, E_, H_, flag);
            ln_kernel<<<R, 256, 0, stream>>>(Y2c, d_in[11], b2o, d_in[12], b2o, E_, flag);
            lif_add_kernel<<<dim3(E_ / 64, CB), 64, 0, stream>>>(Y2c, Xc, At1);
        }
        out_kernel<<<(CB * E_) / 256, 256, 0, stream>>>(Xc, d_out, b0, flag);
    }
}

// Round 9
// 3502.694 us; speedup vs baseline: 2.8817x; 1.0622x over previous
//
#include <hip/hip_runtime.h>
#include <hip/hip_bf16.h>
#include <math.h>

#define B_  256
#define T_  256
#define IN_ 4
#define HP_ 64
#define E_  512
#define H_  1024
#define D_  4

typedef __hip_bfloat16 bf16;
typedef _Float16 f16;
typedef _Float16 f16x8 __attribute__((ext_vector_type(8)));
typedef float f32x4 __attribute__((ext_vector_type(4)));

// ---------------------------------------------------------------------------
// Dual-dtype load helpers: flag!=0 -> input arrays are bf16, else fp32.
// ---------------------------------------------------------------------------
__device__ __forceinline__ float load1(const void* p, size_t idx, bool isb) {
    if (isb) {
        unsigned int u = ((const unsigned short*)p)[idx];
        return __uint_as_float(u << 16);
    }
    return ((const float*)p)[idx];
}

__device__ __forceinline__ float4 load4(const void* p, size_t idx, bool isb) {
    if (isb) {
        ushort4 u = *(const ushort4*)((const unsigned short*)p + idx);
        float4 r;
        r.x = __uint_as_float(((unsigned int)u.x) << 16);
        r.y = __uint_as_float(((unsigned int)u.y) << 16);
        r.z = __uint_as_float(((unsigned int)u.z) << 16);
        r.w = __uint_as_float(((unsigned int)u.w) << 16);
        return r;
    }
    return *((const float4*)p + (idx >> 2));
}

// ---------------------------------------------------------------------------
// Exact 3-plane f16 split:  x ~= h + lb*2^-11  (lb pre-scaled by 2^11).
// x*w = h*wh + (h*2^-11)*(wl*2^11) + (l*2^11)*(wh*2^-11)   [exact terms]
// ---------------------------------------------------------------------------
__device__ __forceinline__ void split3(float x, f16& h, f16& hs, f16& lb) {
    h = (f16)x;
    float hf = (float)h;
    hs = (f16)(hf * 4.8828125e-4f);        // *2^-11 (derived in GEMM)
    lb = (f16)((x - hf) * 2048.0f);        // residual, pre-scaled *2^11
}

// ---------------------------------------------------------------------------
// Dtype sniff (unchanged).
// ---------------------------------------------------------------------------
__global__ void sniff_kernel(const unsigned short* __restrict__ p,
                             int* __restrict__ flag) {
    __shared__ int cnt;
    if (threadIdx.x == 0) cnt = 0;
    __syncthreads();
    int local = 0;
    for (int i = threadIdx.x; i < 65536; i += blockDim.x) {
        unsigned int bits = ((unsigned int)p[i]) << 16;
        float v = __uint_as_float(bits);
        float a = fabsf(v);
        if (!(a <= 1e4f)) local++;
        else if (v != 0.0f && a < 1e-6f) local++;
    }
    atomicAdd(&cnt, local);
    __syncthreads();
    if (threadIdx.x == 0) *flag = (cnt > 1024) ? 0 : 1;
}

// ---------------------------------------------------------------------------
// Weight transpose+split: W[K][N] -> Wt ushort[N][2K]: [h | lb].
// ---------------------------------------------------------------------------
__global__ __launch_bounds__(256) void wsplit_kernel(
        const void* __restrict__ W, size_t wOff, unsigned short* __restrict__ Wt,
        int K, int N, const int* __restrict__ flag) {
    const bool isb = (*flag != 0);
    __shared__ float tile[32][33];
    const int n0 = blockIdx.x * 32, k0 = blockIdx.y * 32;
    const int t = threadIdx.x;
    {
        int lk = t >> 3, ln0 = (t & 7) << 2;
        float4 v = load4(W, wOff + (size_t)(k0 + lk) * N + n0 + ln0, isb);
        tile[lk][ln0 + 0] = v.x; tile[lk][ln0 + 1] = v.y;
        tile[lk][ln0 + 2] = v.z; tile[lk][ln0 + 3] = v.w;
    }
    __syncthreads();
    int n = t >> 3, kq0 = (t & 7) << 2;
    size_t base = (size_t)(n0 + n) * (2 * (size_t)K) + k0 + kq0;
    #pragma unroll
    for (int j = 0; j < 4; ++j) {
        float x = tile[kq0 + j][n];
        f16 h, hs, lb;
        split3(x, h, hs, lb);
        Wt[base + j]     = *(unsigned short*)&h;
        Wt[base + j + K] = *(unsigned short*)&lb;
    }
}

// ---------------------------------------------------------------------------
// MFMA GEMM (structure as R8) + XCD-locality swizzle:
// 1D grid; bid -> (bx,by) with by-panel's gx sharers given bids {k, k+8, ...}
// (same XCD, adjacent dispatch window) so the A panel is fetched into ONE
// XCD's L2 once instead of streamed by all 8.
// ---------------------------------------------------------------------------
template<int NPL>
__device__ __forceinline__ void gemm_mfma_body(
        const unsigned short* __restrict__ At, const unsigned short* __restrict__ Wt,
        const void* __restrict__ bias, size_t bOff,
        float* __restrict__ C, int N, int K, const int* __restrict__ flag) {
    const bool isb = (*flag != 0);
    constexpr int APL = (NPL == 3) ? 2 : 1;      // stored A planes
    __shared__ unsigned short As[128 * 64];      // 16 KB
    __shared__ unsigned short Bs[128 * 64];      // 16 KB

    // ---- XCD-aware bid remap ----
    const int gx = N >> 7;
    const int gy = (int)gridDim.x / gx;
    int bx, by;
    {
        int bid = blockIdx.x;
        if ((gy & 7) == 0) {
            int k = bid & 7, i = bid >> 3;
            bx = i % gx;
            by = (gy >> 3) * k + i / gx;
        } else { bx = bid % gx; by = bid / gx; }
    }
    const int bn = bx * 128;
    const int bm = by * 128;

    const int tid  = threadIdx.x;
    const int lane = tid & 63;
    const int wave = tid >> 6;
    const int wm = wave >> 1;
    const int wn = wave & 1;
    const int g  = lane >> 4;          // k-group 0..3
    const int lr = lane & 15;

    const int sar = tid >> 1;          // A row 0..127
    const int sah = tid & 1;           // A k-half
    const int sbn = tid >> 1;          // B n-row 0..127
    const int sq  = tid & 1;           // B k-half

    const f16 C11 = (f16)4.8828125e-4f;   // 2^-11
    const f16x8 c11v = {C11, C11, C11, C11, C11, C11, C11, C11};

    f32x4 acc[4][4];
    #pragma unroll
    for (int i = 0; i < 4; ++i)
        #pragma unroll
        for (int j = 0; j < 4; ++j) acc[i][j] = (f32x4){0.f, 0.f, 0.f, 0.f};

    const unsigned short* Ap = At + (size_t)(bm + sar) * (APL * (size_t)K) + sah * 16;
    const unsigned short* Wp = Wt + (size_t)(bn + sbn) * (2 * (size_t)K) + sq * 16;

    f16x8 av[2 * APL], wv[4];
    #pragma unroll
    for (int pl = 0; pl < APL; ++pl)
        #pragma unroll
        for (int c = 0; c < 2; ++c)
            av[pl * 2 + c] = *(const f16x8*)(Ap + (size_t)pl * K + c * 8);
    #pragma unroll
    for (int pl = 0; pl < 2; ++pl)
        #pragma unroll
        for (int c = 0; c < 2; ++c)
            wv[pl * 2 + c] = *(const f16x8*)(Wp + (size_t)pl * K + c * 8);

    const int nt = K >> 5;
    for (int t = 0; t < nt; ++t) {
        const int arb = sar * 64, asw = sar & 7;
        #pragma unroll
        for (int pl = 0; pl < APL; ++pl)
            #pragma unroll
            for (int c = 0; c < 2; ++c) {
                const int gg = sah * 2 + c;
                *(f16x8*)&As[arb + (((pl << 2) | gg) ^ asw) * 8] = av[pl * 2 + c];
            }
        const int brb = sbn * 64, bsw = sbn & 7;
        #pragma unroll
        for (int pl = 0; pl < 2; ++pl)
            #pragma unroll
            for (int c = 0; c < 2; ++c) {
                const int gg = sq * 2 + c;
                *(f16x8*)&Bs[brb + (((pl << 2) | gg) ^ bsw) * 8] = wv[pl * 2 + c];
            }
        __syncthreads();
        if (t + 1 < nt) {
            const int k0 = (t + 1) << 5;
            #pragma unroll
            for (int pl = 0; pl < APL; ++pl)
                #pragma unroll
                for (int c = 0; c < 2; ++c)
                    av[pl * 2 + c] = *(const f16x8*)(Ap + (size_t)pl * K + k0 + c * 8);
            #pragma unroll
            for (int pl = 0; pl < 2; ++pl)
                #pragma unroll
                for (int c = 0; c < 2; ++c)
                    wv[pl * 2 + c] = *(const f16x8*)(Wp + (size_t)pl * K + k0 + c * 8);
        }
        f16x8 a0[4], b0[4], b2[4], a2[4];
        #pragma unroll
        for (int mi = 0; mi < 4; ++mi) {
            const int ar = wm * 64 + mi * 16 + lr;
            a0[mi] = *(const f16x8*)&As[ar * 64 + ((g ^ (ar & 7))) * 8];
            if (NPL == 3)
                a2[mi] = *(const f16x8*)&As[ar * 64 + (((4 | g) ^ (ar & 7))) * 8];
        }
        #pragma unroll
        for (int ni = 0; ni < 4; ++ni) {
            const int br = wn * 64 + ni * 16 + lr;
            b0[ni] = *(const f16x8*)&Bs[br * 64 + ((g ^ (br & 7))) * 8];
            b2[ni] = *(const f16x8*)&Bs[br * 64 + (((4 | g) ^ (br & 7))) * 8];
        }
        #pragma unroll
        for (int mi = 0; mi < 4; ++mi)
            #pragma unroll
            for (int ni = 0; ni < 4; ++ni)
                acc[mi][ni] = __builtin_amdgcn_mfma_f32_16x16x32_f16(
                    a0[mi], b0[ni], acc[mi][ni], 0, 0, 0);
        {
            f16x8 a1[4];
            #pragma unroll
            for (int mi = 0; mi < 4; ++mi) a1[mi] = a0[mi] * c11v;
            #pragma unroll
            for (int mi = 0; mi < 4; ++mi)
                #pragma unroll
                for (int ni = 0; ni < 4; ++ni)
                    acc[mi][ni] = __builtin_amdgcn_mfma_f32_16x16x32_f16(
                        a1[mi], b2[ni], acc[mi][ni], 0, 0, 0);
        }
        if (NPL == 3) {
            f16x8 b1[4];
            #pragma unroll
            for (int ni = 0; ni < 4; ++ni) b1[ni] = b0[ni] * c11v;
            #pragma unroll
            for (int mi = 0; mi < 4; ++mi)
                #pragma unroll
                for (int ni = 0; ni < 4; ++ni)
                    acc[mi][ni] = __builtin_amdgcn_mfma_f32_16x16x32_f16(
                        a2[mi], b1[ni], acc[mi][ni], 0, 0, 0);
        }
        __syncthreads();
    }
    #pragma unroll
    for (int ni = 0; ni < 4; ++ni) {
        const int col = bn + wn * 64 + ni * 16 + lr;
        const float bv = load1(bias, bOff + col, isb);
        #pragma unroll
        for (int mi = 0; mi < 4; ++mi) {
            #pragma unroll
            for (int r = 0; r < 4; ++r) {
                const size_t row = (size_t)(bm + wm * 64 + mi * 16 + g * 4 + r);
                C[row * N + col] = acc[mi][ni][r] + bv;
            }
        }
    }
}

__global__ __launch_bounds__(256, 3) void gemm_mfma3_kernel(
        const unsigned short* __restrict__ At, const unsigned short* __restrict__ Wt,
        const void* __restrict__ bias, size_t bOff,
        float* __restrict__ C, int N, int K, const int* __restrict__ flag) {
    gemm_mfma_body<3>(At, Wt, bias, bOff, C, N, K, flag);
}

__global__ __launch_bounds__(256, 3) void gemm_mfma2_kernel(
        const unsigned short* __restrict__ At, const unsigned short* __restrict__ Wt,
        const void* __restrict__ bias, size_t bOff,
        float* __restrict__ C, int N, int K, const int* __restrict__ flag) {
    gemm_mfma_body<2>(At, Wt, bias, bOff, C, N, K, flag);
}

// ---------------------------------------------------------------------------
// Projector (unchanged from R8).
// ---------------------------------------------------------------------------
#define RB_ 16
__global__ __launch_bounds__(256) void proj_kernel(
        const void* __restrict__ hist, const void* __restrict__ pW1,
        const void* __restrict__ pb1,  const void* __restrict__ pW2,
        const void* __restrict__ pb2,  float* __restrict__ Xc,
        unsigned short* __restrict__ At1,
        size_t m0, const int* __restrict__ flag) {
    const bool isb = (*flag != 0);
    __shared__ float h1[RB_][HP_];
    const size_t mb = (size_t)blockIdx.x * RB_;
    const int tid = threadIdx.x;
    const int lane = tid & 63;
    const int grp = tid >> 6;
    #pragma unroll
    for (int rep = 0; rep < 4; ++rep) {
        int idx = tid + rep * 256;
        int r = idx >> 6, c = idx & 63;
        size_t gm = m0 + mb + r;
        float acc = 0.f;
        #pragma unroll
        for (int i = 0; i < IN_; ++i)
            acc = fmaf(load1(hist, gm * IN_ + i, isb),
                       load1(pW1, (size_t)i * HP_ + c, isb), acc);
        acc += load1(pb1, c, isb);
        h1[r][c] = 0.5f * acc * (1.0f + erff(acc * 0.70710678118654752440f));
    }
    __syncthreads();
    const int e0 = lane * 8;
    float acc[4][8];
    #pragma unroll
    for (int r = 0; r < 4; ++r)
        #pragma unroll
        for (int j = 0; j < 8; ++j) acc[r][j] = 0.f;
    for (int i = 0; i < HP_; ++i) {
        float4 wA = load4(pW2, (size_t)i * E_ + e0, isb);
        float4 wB = load4(pW2, (size_t)i * E_ + e0 + 4, isb);
        float w[8] = {wA.x, wA.y, wA.z, wA.w, wB.x, wB.y, wB.z, wB.w};
        #pragma unroll
        for (int r = 0; r < 4; ++r) {
            float h = h1[grp * 4 + r][i];
            #pragma unroll
            for (int j = 0; j < 8; ++j) acc[r][j] = fmaf(h, w[j], acc[r][j]);
        }
    }
    #pragma unroll
    for (int r = 0; r < 4; ++r) {
        size_t row = mb + grp * 4 + r;
        float o[8];
        #pragma unroll
        for (int j = 0; j < 8; ++j)
            o[j] = acc[r][j] + load1(pb2, e0 + j, isb);
        *(float4*)(Xc + row * E_ + e0)     = (float4){o[0], o[1], o[2], o[3]};
        *(float4*)(Xc + row * E_ + e0 + 4) = (float4){o[4], o[5], o[6], o[7]};
        f16x8 hv, lv;
        #pragma unroll
        for (int j = 0; j < 8; ++j) {
            f16 h, hs, lb;
            split3(o[j], h, hs, lb);
            hv[j] = h; lv[j] = lb;
        }
        *(f16x8*)&At1[row * (2 * E_) + e0]      = hv;
        *(f16x8*)&At1[row * (2 * E_) + E_ + e0] = lv;
    }
}

// ---------------------------------------------------------------------------
// LayerNorm stats only: same block_sum tree -> bit-identical mean/denom.
// Affine apply moved into the LIF kernels (identical per-element expr).
// ---------------------------------------------------------------------------
__device__ __forceinline__ float block_sum(float v, float* smem, int tid) {
    #pragma unroll
    for (int off = 32; off > 0; off >>= 1) v += __shfl_down(v, off, 64);
    __syncthreads();
    if ((tid & 63) == 0) smem[tid >> 6] = v;
    __syncthreads();
    if (tid == 0) smem[4] = smem[0] + smem[1] + smem[2] + smem[3];
    __syncthreads();
    return smem[4];
}

__global__ __launch_bounds__(256) void ln_stats_kernel(const float* __restrict__ Y,
                                                       float* __restrict__ stats,
                                                       int N) {
    __shared__ float smem[5];
    size_t row = blockIdx.x;
    const float* y = Y + row * (size_t)N;
    int tid = threadIdx.x;
    int nPer = N >> 8;
    float vals[4];
    float s = 0.f;
    for (int i = 0; i < nPer; ++i) { float v = y[tid + (i << 8)]; vals[i] = v; s += v; }
    float mean = block_sum(s, smem, tid) / (float)N;
    float sq = 0.f;
    for (int i = 0; i < nPer; ++i) { float d0 = vals[i] - mean; sq += d0 * d0; }
    float var = block_sum(sq, smem, tid) / (float)N;
    if (tid == 0) {
        stats[row * 2]     = mean;
        stats[row * 2 + 1] = sqrtf(var + 1e-5f);
    }
}

// ---------------------------------------------------------------------------
// LIF scan with fused LN-apply: xn = (x-mean)/denom*g+b (identical expression
// to the old ln_kernel write), then the LIF update. Bit-identical pipeline.
// ---------------------------------------------------------------------------
__global__ __launch_bounds__(64) void lif_kernel(const float* __restrict__ Y,
                                                 const float* __restrict__ stats,
                                                 const void* __restrict__ g, size_t gOff,
                                                 const void* __restrict__ b, size_t bOff,
                                                 unsigned short* __restrict__ At2,
                                                 int N, const int* __restrict__ flag) {
    const bool isb = (*flag != 0);
    int f = blockIdx.x * 64 + threadIdx.x;
    int bb = blockIdx.y;
    const float gw = load1(g, gOff + f, isb);
    const float bw = load1(b, bOff + f, isb);
    size_t base = (size_t)bb * T_ * N + f;
    size_t srow = (size_t)bb * T_;
    float v = 0.f;
    for (int t0 = 0; t0 < T_; t0 += 8) {
        float x[8], mn[8], dn[8], s[8];
        #pragma unroll
        for (int j = 0; j < 8; ++j) {
            x[j]  = Y[base + (size_t)(t0 + j) * N];
            mn[j] = stats[(srow + t0 + j) * 2];
            dn[j] = stats[(srow + t0 + j) * 2 + 1];
        }
        #pragma unroll
        for (int j = 0; j < 8; ++j) {
            float xn = (x[j] - mn[j]) / dn[j] * gw + bw;
            v = v + (xn - v) * 0.5f;
            s[j] = (v - 1.0f >= 0.0f) ? 1.0f : 0.0f;
            v = v * (1.0f - s[j]);
        }
        #pragma unroll
        for (int j = 0; j < 8; ++j) {
            f16 h = (f16)s[j];
            At2[base + (size_t)(t0 + j) * N] = *(unsigned short*)&h;
        }
    }
}

// Second LIF: fused LN-apply + residual add into Xc + {h,lb} split to At1.
__global__ __launch_bounds__(64) void lif_add_kernel(const float* __restrict__ Z,
                                                     const float* __restrict__ stats,
                                                     const void* __restrict__ g, size_t gOff,
                                                     const void* __restrict__ b, size_t bOff,
                                                     float* __restrict__ Xc,
                                                     unsigned short* __restrict__ At1,
                                                     const int* __restrict__ flag) {
    const bool isb = (*flag != 0);
    int e = blockIdx.x * 64 + threadIdx.x;
    int bb = blockIdx.y;
    const float gw = load1(g, gOff + e, isb);
    const float bw = load1(b, bOff + e, isb);
    size_t base  = (size_t)bb * T_ * E_ + e;
    size_t base2 = (size_t)bb * T_ * (2 * E_) + e;
    size_t srow  = (size_t)bb * T_;
    float v = 0.f;
    for (int t0 = 0; t0 < T_; t0 += 8) {
        float x[8], xc[8], mn[8], dn[8], s[8];
        #pragma unroll
        for (int j = 0; j < 8; ++j) {
            x[j]  = Z[base + (size_t)(t0 + j) * E_];
            mn[j] = stats[(srow + t0 + j) * 2];
            dn[j] = stats[(srow + t0 + j) * 2 + 1];
        }
        #pragma unroll
        for (int j = 0; j < 8; ++j) xc[j] = Xc[base + (size_t)(t0 + j) * E_];
        #pragma unroll
        for (int j = 0; j < 8; ++j) {
            float xn = (x[j] - mn[j]) / dn[j] * gw + bw;
            v = v + (xn - v) * 0.5f;
            s[j] = (v - 1.0f >= 0.0f) ? 1.0f : 0.0f;
            v = v * (1.0f - s[j]);
        }
        #pragma unroll
        for (int j = 0; j < 8; ++j) {
            float nx = xc[j] + s[j];
            Xc[base + (size_t)(t0 + j) * E_] = nx;
            f16 h, hs, lb;
            split3(nx, h, hs, lb);
            At1[base2 + (size_t)(t0 + j) * (2 * E_)]      = *(unsigned short*)&h;
            At1[base2 + (size_t)(t0 + j) * (2 * E_) + E_] = *(unsigned short*)&lb;
        }
    }
}

__global__ void out_kernel(const float* __restrict__ Xc, void* __restrict__ out,
                           int b0, const int* __restrict__ flag) {
    int i = blockIdx.x * 256 + threadIdx.x;
    int bl = i / E_, e = i - bl * E_;
    float v = Xc[((size_t)bl * T_ + (T_ - 1)) * E_ + e];
    size_t oi = (size_t)(b0 + bl) * E_ + e;
    if (*flag) ((bf16*)out)[oi] = __float2bfloat16(v);
    else       ((float*)out)[oi] = v;
}

// ---------------------------------------------------------------------------
extern "C" void kernel_launch(void* const* d_in, const int* in_sizes, int n_in,
                              void* d_out, int out_size, void* d_ws, size_t ws_size,
                              hipStream_t stream) {
    char* ws = (char*)d_ws;
    int* flag = (int*)ws;

    const size_t wtCount = 2 * (size_t)E_ * H_;
    const size_t wtBytes = 2 * D_ * wtCount * sizeof(unsigned short); // ~16.8 MB
    unsigned short* Wt1 = (unsigned short*)(ws + 256);
    unsigned short* Wt2 = Wt1 + (size_t)D_ * wtCount;

    size_t used = 256 + wtBytes;
    size_t avail = (ws_size > used) ? ws_size - used : 0;
    // per batch: fp32 bufs + At1 + At2 + stats (2 bufs x 2 floats/row)
    const size_t perBatch = (size_t)T_ * ((E_ + H_ + E_) * 4 + 2 * E_ * 2 + H_ * 2 + 16);
    int CB = 256;
    while (CB > 1 && (size_t)CB * perBatch > avail) CB >>= 1;
    const int R = CB * T_;

    float* Xc  = (float*)(ws + used);
    float* HBc = Xc + (size_t)R * E_;
    float* Y2c = HBc + (size_t)R * H_;
    unsigned short* At1 = (unsigned short*)(Y2c + (size_t)R * E_);
    unsigned short* At2 = At1 + (size_t)R * 2 * E_;
    float* St1 = (float*)(At2 + (size_t)R * H_);
    float* St2 = St1 + (size_t)R * 2;

    sniff_kernel<<<1, 256, 0, stream>>>((const unsigned short*)d_in[0], flag);

    for (int d = 0; d < D_; ++d) {
        wsplit_kernel<<<dim3(H_ / 32, E_ / 32), 256, 0, stream>>>(
            d_in[5], (size_t)d * E_ * H_, Wt1 + (size_t)d * wtCount, E_, H_, flag);
        wsplit_kernel<<<dim3(E_ / 32, H_ / 32), 256, 0, stream>>>(
            d_in[9], (size_t)d * H_ * E_, Wt2 + (size_t)d * wtCount, H_, E_, flag);
    }

    for (int b0 = 0; b0 < B_; b0 += CB) {
        proj_kernel<<<R / RB_, 256, 0, stream>>>(d_in[0], d_in[1], d_in[2], d_in[3],
                                                 d_in[4], Xc, At1, (size_t)b0 * T_, flag);
        for (int d = 0; d < D_; ++d) {
            size_t b1o = (size_t)d * H_;
            size_t b2o = (size_t)d * E_;

            gemm_mfma3_kernel<<<(H_ / 128) * (R / 128), 256, 0, stream>>>(
                At1, Wt1 + (size_t)d * wtCount, d_in[6], b1o, HBc, H_, E_, flag);
            ln_stats_kernel<<<R, 256, 0, stream>>>(HBc, St1, H_);
            lif_kernel<<<dim3(H_ / 64, CB), 64, 0, stream>>>(
                HBc, St1, d_in[7], b1o, d_in[8], b1o, At2, H_, flag);

            gemm_mfma2_kernel<<<(E_ / 128) * (R / 128), 256, 0, stream>>>(
                At2, Wt2 + (size_t)d * wtCount, d_in[10], b2o, Y2c, E_, H_, flag);
            ln_stats_kernel<<<R, 256, 0, stream>>>(Y2c, St2, E_);
            lif_add_kernel<<<dim3(E_ / 64, CB), 64, 0, stream>>>(
                Y2c, St2, d_in[11], b2o, d_in[12], b2o, Xc, At1, flag);
        }
        out_kernel<<<(CB * E_) / 256, 256, 0, stream>>>(Xc, d_out, b0, flag);
    }
}